// Round 1
// baseline (1088.892 us; speedup 1.0000x reference)
//
#include <hip/hip_runtime.h>

#define N_PTS 4096
#define KNBR 40
#define BATCH 4

__device__ __forceinline__ float lrelu(float v) { return v > 0.0f ? v : 0.2f * v; }

// ---------------- KNN: exact top-40 per row via binary search on ordered-uint space ----------------
__global__ __launch_bounds__(256) void knn_kernel(const float* __restrict__ x, int* __restrict__ idxo)
{
    const int t = threadIdx.x;
    const int pt = blockIdx.x;
    const int b = pt >> 12, n = pt & 4095;
    const float* xb = x + b * 3 * N_PTS;
    const int lane = t & 63, wv = t >> 6;

    __shared__ unsigned wcnt[2][4];
    __shared__ int wpos_s, tcnt_s;
    __shared__ int ties[64];

    const float c0 = xb[n], c1 = xb[N_PTS + n], c2 = xb[2 * N_PTS + n];
    const float cc = c0 * c0 + c1 * c1 + c2 * c2;

    unsigned ov[16];
#pragma unroll
    for (int j = 0; j < 16; ++j) {
        int m = t + j * 256;
        float a0 = xb[m], a1 = xb[N_PTS + m], a2 = xb[2 * N_PTS + m];
        float d = 2.0f * (c0 * a0 + c1 * a1 + c2 * a2) - cc - (a0 * a0 + a1 * a1 + a2 * a2);
        unsigned u = __float_as_uint(d);
        ov[j] = (u & 0x80000000u) ? ~u : (u | 0x80000000u);
    }
    if (t == 0) { wpos_s = 0; tcnt_s = 0; }

    // find v* = 40th largest ov (value-level; ties resolved after)
    unsigned lo = 0u, hi = 0xFFFFFFFFu;
    int it = 0;
    while (lo < hi) {
        unsigned span = hi - lo;
        unsigned mid = lo + (span >> 1) + (span & 1u);   // ceil-mid, no overflow
        int c = 0;
#pragma unroll
        for (int j = 0; j < 16; ++j) c += (ov[j] >= mid) ? 1 : 0;
#pragma unroll
        for (int off = 32; off > 0; off >>= 1) c += __shfl_down(c, off, 64);
        int p = it & 1;
        if (lane == 0) wcnt[p][wv] = (unsigned)c;
        __syncthreads();
        unsigned tot = wcnt[p][0] + wcnt[p][1] + wcnt[p][2] + wcnt[p][3];
        if (tot >= (unsigned)KNBR) lo = mid; else hi = mid - 1u;
        ++it;
    }
    const unsigned vstar = lo;
    __syncthreads();
#pragma unroll
    for (int j = 0; j < 16; ++j) {
        int m = t + j * 256;
        if (ov[j] > vstar) {
            int p = atomicAdd(&wpos_s, 1);
            idxo[pt * KNBR + p] = m;
        } else if (ov[j] == vstar) {
            int q = atomicAdd(&tcnt_s, 1);
            if (q < 64) ties[q] = m;
        }
    }
    __syncthreads();
    if (t == 0) {
        int c1n = wpos_s;           // count strictly above v*  (< 40 by construction)
        int R = KNBR - c1n;         // fill remainder with smallest indices among == v*
        int tc = tcnt_s < 64 ? tcnt_s : 64;
        for (int r = 0; r < R; ++r) {
            int bi = 0, bm = 0x7FFFFFFF;
            for (int q = 0; q < tc; ++q) {
                if (ties[q] < bm) { bm = ties[q]; bi = q; }
            }
            ties[bi] = 0x7FFFFFFF;
            idxo[pt * KNBR + c1n + r] = bm;
        }
    }
}

// ---------------- Layer 1: gather + conv1(6->64) + conv2(64->64) + max over k, fused per point ----------------
__global__ __launch_bounds__(256) void layer1_kernel(const float* __restrict__ x, const int* __restrict__ idx,
    const float* __restrict__ W1, const float* __restrict__ s1, const float* __restrict__ b1,
    const float* __restrict__ W2, const float* __restrict__ s2, const float* __restrict__ b2,
    float* __restrict__ x1out)
{
    const int t = threadIdx.x;
    const int pt = blockIdx.x;
    const int b = pt >> 12, n = pt & 4095;
    const float* xb = x + b * 3 * N_PTS;

    __shared__ float w1s[384];
    __shared__ float s1s[64], b1s[64], ctrvs[64];
    __shared__ int idxs[KNBR];
    __shared__ float nbr[KNBR][4];
    __shared__ float As[64][44];   // y1 transposed: [feat o][k]
    __shared__ float Bs[64][68];   // W2^T: [i][o]
    __shared__ float red[16][64];

    if (t < KNBR) idxs[t] = idx[pt * KNBR + t];
    if (t < 64) { s1s[t] = s1[t]; b1s[t] = b1[t]; }
    if (t < 128) { w1s[t] = W1[t]; w1s[t + 128] = W1[t + 128]; w1s[t + 256] = W1[t + 256]; }
    const float c0 = xb[n], c1 = xb[N_PTS + n], c2 = xb[2 * N_PTS + n];
    __syncthreads();
    if (t < 120) { int k = t / 3, c = t % 3; nbr[k][c] = xb[c * N_PTS + idxs[k]]; }
    if (t < 64) {
        int o = t;
        ctrvs[o] = (w1s[o*6+3] - w1s[o*6+0]) * c0 + (w1s[o*6+4] - w1s[o*6+1]) * c1
                 + (w1s[o*6+5] - w1s[o*6+2]) * c2;
    }
    {
        int o = t >> 2, i4 = (t & 3) * 4;
#pragma unroll
        for (int r = 0; r < 4; ++r) {
            int i0 = i4 + r * 16;
            float4 wvv = *reinterpret_cast<const float4*>(&W2[o * 64 + i0]);
            Bs[i0 + 0][o] = wvv.x; Bs[i0 + 1][o] = wvv.y; Bs[i0 + 2][o] = wvv.z; Bs[i0 + 3][o] = wvv.w;
        }
    }
    __syncthreads();
#pragma unroll
    for (int r = 0; r < 10; ++r) {
        int e = r * 256 + t;
        int k = e >> 6, o = e & 63;
        float v = w1s[o*6+0] * nbr[k][0] + w1s[o*6+1] * nbr[k][1] + w1s[o*6+2] * nbr[k][2] + ctrvs[o];
        As[o][k] = lrelu(v * s1s[o] + b1s[o]);
    }
    __syncthreads();
    const int tm = t & 15, tn = t >> 4;
    if (tm < 10) {
        float acc[4][4] = {};
#pragma unroll 8
        for (int kk = 0; kk < 64; ++kk) {
            float4 a = *reinterpret_cast<const float4*>(&As[kk][tm * 4]);
            float4 b4 = *reinterpret_cast<const float4*>(&Bs[kk][tn * 4]);
            float av[4] = {a.x, a.y, a.z, a.w};
            float bv[4] = {b4.x, b4.y, b4.z, b4.w};
#pragma unroll
            for (int i = 0; i < 4; ++i)
#pragma unroll
                for (int j = 0; j < 4; ++j) acc[i][j] = fmaf(av[i], bv[j], acc[i][j]);
        }
#pragma unroll
        for (int j = 0; j < 4; ++j) {
            int o = tn * 4 + j;
            float sv = s2[o], bvv = b2[o];
            float mx = -1e30f;
#pragma unroll
            for (int i = 0; i < 4; ++i) mx = fmaxf(mx, lrelu(acc[i][j] * sv + bvv));
            red[tm][o] = mx;
        }
    }
    __syncthreads();
    if (t < 64) {
        float m = red[0][t];
#pragma unroll
        for (int q = 1; q < 10; ++q) m = fmaxf(m, red[q][t]);
        x1out[pt * 64 + t] = m;
    }
}

// ---------------- Edge layers 2/3: gather + conv(128->64 factored) [+ conv(64->64)] + max, fused ----------------
template<int HAS2>
__global__ __launch_bounds__(256) void edge_kernel(const float* __restrict__ src, const int* __restrict__ idx,
    const float* __restrict__ Wa, const float* __restrict__ sa, const float* __restrict__ ba,
    const float* __restrict__ Wb, const float* __restrict__ sb, const float* __restrict__ bb,
    float* __restrict__ xout)
{
    const int t = threadIdx.x;
    const int pt = blockIdx.x;
    const int b = pt >> 12;

    __shared__ int idxs[KNBR];
    __shared__ float ctr1[64], ctrvs[64];
    __shared__ float part[4][64];
    __shared__ float As0[64][44];   // gathered neighbor feats: [i][k]
    __shared__ float Bs[64][68];    // Wa_a^T then Wb^T (reused)
    __shared__ float As1[64][44];   // y1: [o][k]
    __shared__ float red[16][64];

    if (t < KNBR) idxs[t] = idx[pt * KNBR + t];
    if (t < 64) ctr1[t] = src[pt * 64 + t];
    __syncthreads();
    {
        const int i = t & 63, kb = t >> 6;
#pragma unroll
        for (int r = 0; r < 10; ++r) {
            int k = kb + r * 4;
            As0[i][k] = src[(b * N_PTS + idxs[k]) * 64 + i];
        }
    }
    {
        int o = t >> 2, i4 = (t & 3) * 4;
#pragma unroll
        for (int r = 0; r < 4; ++r) {
            int i0 = i4 + r * 16;
            float4 wvv = *reinterpret_cast<const float4*>(&Wa[o * 128 + i0]);
            Bs[i0+0][o] = wvv.x; Bs[i0+1][o] = wvv.y; Bs[i0+2][o] = wvv.z; Bs[i0+3][o] = wvv.w;
        }
    }
    {
        int o = t & 63, i0 = (t >> 6) * 16;
        float s = 0.0f;
#pragma unroll
        for (int q = 0; q < 16; ++q) {
            int i = i0 + q;
            s += (Wa[o * 128 + 64 + i] - Wa[o * 128 + i]) * ctr1[i];
        }
        part[t >> 6][o] = s;
    }
    __syncthreads();
    if (t < 64) ctrvs[t] = part[0][t] + part[1][t] + part[2][t] + part[3][t];
    __syncthreads();

    const int tm = t & 15, tn = t >> 4;
    if (tm < 10) {
        float acc[4][4] = {};
#pragma unroll 8
        for (int kk = 0; kk < 64; ++kk) {
            float4 a = *reinterpret_cast<const float4*>(&As0[kk][tm * 4]);
            float4 b4 = *reinterpret_cast<const float4*>(&Bs[kk][tn * 4]);
            float av[4] = {a.x,a.y,a.z,a.w}, bv[4] = {b4.x,b4.y,b4.z,b4.w};
#pragma unroll
            for (int i = 0; i < 4; ++i)
#pragma unroll
                for (int j = 0; j < 4; ++j) acc[i][j] = fmaf(av[i], bv[j], acc[i][j]);
        }
        if (HAS2) {
#pragma unroll
            for (int j = 0; j < 4; ++j) {
                int o = tn * 4 + j;
                float sv = sa[o], bvv = ba[o], cv = ctrvs[o];
#pragma unroll
                for (int i = 0; i < 4; ++i)
                    As1[o][tm * 4 + i] = lrelu((acc[i][j] + cv) * sv + bvv);
            }
        } else {
#pragma unroll
            for (int j = 0; j < 4; ++j) {
                int o = tn * 4 + j;
                float sv = sa[o], bvv = ba[o], cv = ctrvs[o];
                float mx = -1e30f;
#pragma unroll
                for (int i = 0; i < 4; ++i)
                    mx = fmaxf(mx, lrelu((acc[i][j] + cv) * sv + bvv));
                red[tm][o] = mx;
            }
        }
    }
    __syncthreads();
    if (HAS2) {
        {
            int o = t >> 2, i4 = (t & 3) * 4;
#pragma unroll
            for (int r = 0; r < 4; ++r) {
                int i0 = i4 + r * 16;
                float4 wvv = *reinterpret_cast<const float4*>(&Wb[o * 64 + i0]);
                Bs[i0+0][o] = wvv.x; Bs[i0+1][o] = wvv.y; Bs[i0+2][o] = wvv.z; Bs[i0+3][o] = wvv.w;
            }
        }
        __syncthreads();
        if (tm < 10) {
            float acc[4][4] = {};
#pragma unroll 8
            for (int kk = 0; kk < 64; ++kk) {
                float4 a = *reinterpret_cast<const float4*>(&As1[kk][tm * 4]);
                float4 b4 = *reinterpret_cast<const float4*>(&Bs[kk][tn * 4]);
                float av[4] = {a.x,a.y,a.z,a.w}, bv[4] = {b4.x,b4.y,b4.z,b4.w};
#pragma unroll
                for (int i = 0; i < 4; ++i)
#pragma unroll
                    for (int j = 0; j < 4; ++j) acc[i][j] = fmaf(av[i], bv[j], acc[i][j]);
            }
#pragma unroll
            for (int j = 0; j < 4; ++j) {
                int o = tn * 4 + j;
                float sv = sb[o], bvv = bb[o];
                float mx = -1e30f;
#pragma unroll
                for (int i = 0; i < 4; ++i)
                    mx = fmaxf(mx, lrelu(acc[i][j] * sv + bvv));
                red[tm][o] = mx;
            }
        }
        __syncthreads();
    }
    if (t < 64) {
        float m = red[0][t];
#pragma unroll
        for (int q = 1; q < 10; ++q) m = fmaxf(m, red[q][t]);
        xout[pt * 64 + t] = m;
    }
}

// ---------------- Generic 64x64-tile GEMM with fused epilogues ----------------
// MODE 0: conv6  (A=xcat K=192, lrelu, per-tile row-max -> gpart)
// MODE 1: conv7  (A=xcat K=192, +c7[b][o], lrelu -> h7)
// MODE 2: conv8  (A=h7 K=512, lrelu -> h8)
// MODE 3: conv9  (A=h8 K=256, +b9, transposed store, o<63)
template<int KD, int MODE, int NTOT, int LDB, int BOFF>
__global__ __launch_bounds__(256) void gemm_kernel(const float* __restrict__ A0, const float* __restrict__ A1,
    const float* __restrict__ A2, const float* __restrict__ Bw,
    const float* __restrict__ sv, const float* __restrict__ bv,
    const float* __restrict__ extra, float* __restrict__ outp)
{
    const int t = threadIdx.x;
    const int m0 = blockIdx.x * 64;
    const int n0 = blockIdx.y * 64;
    __shared__ float As[16][68];
    __shared__ float Bs[16][68];
    __shared__ float red[16][64];
    const int mrow = t >> 2, kq = (t & 3) * 4;
    const int tm = t & 15, tn = t >> 4;
    float acc[4][4] = {};
    for (int ks = 0; ks < KD; ks += 16) {
        float4 av;
        if (MODE == 0 || MODE == 1) {
            int k = ks + kq;
            const float* srcp = (k < 64) ? A0 : ((k < 128) ? A1 : A2);
            av = *reinterpret_cast<const float4*>(&srcp[(m0 + mrow) * 64 + (k & 63)]);
        } else {
            av = *reinterpret_cast<const float4*>(&A0[(m0 + mrow) * KD + ks + kq]);
        }
        As[kq+0][mrow] = av.x; As[kq+1][mrow] = av.y; As[kq+2][mrow] = av.z; As[kq+3][mrow] = av.w;
        float4 bw;
        {
            int o = n0 + mrow;
            if (MODE == 3 && o >= 63) bw = make_float4(0.f, 0.f, 0.f, 0.f);
            else bw = *reinterpret_cast<const float4*>(&Bw[o * LDB + BOFF + ks + kq]);
        }
        Bs[kq+0][mrow] = bw.x; Bs[kq+1][mrow] = bw.y; Bs[kq+2][mrow] = bw.z; Bs[kq+3][mrow] = bw.w;
        __syncthreads();
#pragma unroll
        for (int kk = 0; kk < 16; ++kk) {
            float4 a = *reinterpret_cast<const float4*>(&As[kk][tm * 4]);
            float4 b4 = *reinterpret_cast<const float4*>(&Bs[kk][tn * 4]);
            float avr[4] = {a.x,a.y,a.z,a.w}, bvr[4] = {b4.x,b4.y,b4.z,b4.w};
#pragma unroll
            for (int i = 0; i < 4; ++i)
#pragma unroll
                for (int j = 0; j < 4; ++j) acc[i][j] = fmaf(avr[i], bvr[j], acc[i][j]);
        }
        __syncthreads();
    }
    if (MODE == 0) {
#pragma unroll
        for (int j = 0; j < 4; ++j) {
            int o = n0 + tn * 4 + j;
            float s = sv[o], bbv = bv[o];
            float m = -1e30f;
#pragma unroll
            for (int i = 0; i < 4; ++i) m = fmaxf(m, lrelu(acc[i][j] * s + bbv));
            red[tm][tn * 4 + j] = m;
        }
        __syncthreads();
        if (t < 64) {
            float m = red[0][t];
#pragma unroll
            for (int q = 1; q < 16; ++q) m = fmaxf(m, red[q][t]);
            outp[blockIdx.x * NTOT + n0 + t] = m;
        }
    } else if (MODE == 1) {
        const int bidx = m0 >> 12;
#pragma unroll
        for (int i = 0; i < 4; ++i) {
            float4 w;
            float* wp = &w.x;
#pragma unroll
            for (int j = 0; j < 4; ++j) {
                int o = n0 + tn * 4 + j;
                wp[j] = lrelu((acc[i][j] + extra[bidx * 512 + o]) * sv[o] + bv[o]);
            }
            *reinterpret_cast<float4*>(&outp[(m0 + tm * 4 + i) * NTOT + n0 + tn * 4]) = w;
        }
    } else if (MODE == 2) {
#pragma unroll
        for (int i = 0; i < 4; ++i) {
            float4 w;
            float* wp = &w.x;
#pragma unroll
            for (int j = 0; j < 4; ++j) {
                int o = n0 + tn * 4 + j;
                wp[j] = lrelu(acc[i][j] * sv[o] + bv[o]);
            }
            *reinterpret_cast<float4*>(&outp[(m0 + tm * 4 + i) * NTOT + n0 + tn * 4]) = w;
        }
    } else {
        const int bidx = m0 >> 12;
        const int nb = m0 & 4095;
#pragma unroll
        for (int j = 0; j < 4; ++j) {
            int o = tn * 4 + j;
            if (o < 63) {
                float b9v = bv[o];
                float4 w;
                w.x = acc[0][j] + b9v; w.y = acc[1][j] + b9v; w.z = acc[2][j] + b9v; w.w = acc[3][j] + b9v;
                *reinterpret_cast<float4*>(&outp[(bidx * 63 + o) * N_PTS + nb + tm * 4]) = w;
            }
        }
    }
}

// ---------------- small reduction kernels ----------------
__global__ __launch_bounds__(256) void greduce_kernel(const float* __restrict__ gpart, float* __restrict__ g)
{
    int tid = blockIdx.x * 256 + threadIdx.x;   // 4096
    int b = tid >> 10, o = tid & 1023;
    float m = -1e30f;
    for (int q = 0; q < 64; ++q) m = fmaxf(m, gpart[(b * 64 + q) * 1024 + o]);
    g[tid] = m;
}

__global__ __launch_bounds__(256) void c7_kernel(const float* __restrict__ g, const float* __restrict__ W7,
                                                 float* __restrict__ c7)
{
    int tid = blockIdx.x * 256 + threadIdx.x;   // 2048
    int b = tid >> 9, o = tid & 511;
    const float* gb = g + b * 1024;
    const float* wr = W7 + o * 1216;
    float s = 0.0f;
    for (int i = 0; i < 1024; i += 4) {
        float4 wv4 = *reinterpret_cast<const float4*>(&wr[i]);
        float4 gv4 = *reinterpret_cast<const float4*>(&gb[i]);
        s += wv4.x * gv4.x + wv4.y * gv4.y + wv4.z * gv4.z + wv4.w * gv4.w;
    }
    c7[tid] = s;
}

extern "C" void kernel_launch(void* const* d_in, const int* in_sizes, int n_in,
                              void* d_out, int out_size, void* d_ws, size_t ws_size,
                              hipStream_t stream)
{
    const float* x  = (const float*)d_in[0];
    const float* W1 = (const float*)d_in[1];
    const float* s1 = (const float*)d_in[2];
    const float* b1 = (const float*)d_in[3];
    const float* W2 = (const float*)d_in[4];
    const float* s2 = (const float*)d_in[5];
    const float* b2 = (const float*)d_in[6];
    const float* W3 = (const float*)d_in[7];
    const float* s3 = (const float*)d_in[8];
    const float* b3 = (const float*)d_in[9];
    const float* W4 = (const float*)d_in[10];
    const float* s4 = (const float*)d_in[11];
    const float* b4 = (const float*)d_in[12];
    const float* W5 = (const float*)d_in[13];
    const float* s5 = (const float*)d_in[14];
    const float* b5 = (const float*)d_in[15];
    const float* W6 = (const float*)d_in[16];
    const float* s6 = (const float*)d_in[17];
    const float* b6 = (const float*)d_in[18];
    const float* W7 = (const float*)d_in[19];
    const float* s7 = (const float*)d_in[20];
    const float* b7 = (const float*)d_in[21];
    const float* W8 = (const float*)d_in[22];
    const float* s8 = (const float*)d_in[23];
    const float* b8 = (const float*)d_in[24];
    const float* W9 = (const float*)d_in[25];
    const float* b9 = (const float*)d_in[26];

    char* ws = (char*)d_ws;
    int*   idx   = (int*)(ws);                       // 655360 int        ( 2.62 MB)
    float* x1    = (float*)(ws + 2621440);           // 1048576 f         ( 4.19 MB)
    float* x2    = (float*)(ws + 6815744);
    float* x3    = (float*)(ws + 11010048);
    float* gpart = (float*)(ws + 15204352);          // 262144 f          ( 1.05 MB)
    float* g     = (float*)(ws + 16252928);          // 4096 f
    float* c7    = (float*)(ws + 16269312);          // 2048 f
    float* h7    = (float*)(ws + 16277504);          // 8388608 f         (33.6 MB)
    float* h8    = (float*)(ws + 49831936);          // 4194304 f         (16.8 MB)
    float* outp  = (float*)d_out;

    knn_kernel<<<BATCH * N_PTS, 256, 0, stream>>>(x, idx);
    layer1_kernel<<<BATCH * N_PTS, 256, 0, stream>>>(x, idx, W1, s1, b1, W2, s2, b2, x1);
    edge_kernel<1><<<BATCH * N_PTS, 256, 0, stream>>>(x1, idx, W3, s3, b3, W4, s4, b4, x2);
    edge_kernel<0><<<BATCH * N_PTS, 256, 0, stream>>>(x2, idx, W5, s5, b5, nullptr, nullptr, nullptr, x3);
    gemm_kernel<192, 0, 1024, 192, 0><<<dim3(256, 16), 256, 0, stream>>>(x1, x2, x3, W6, s6, b6, nullptr, gpart);
    greduce_kernel<<<16, 256, 0, stream>>>(gpart, g);
    c7_kernel<<<8, 256, 0, stream>>>(g, W7, c7);
    gemm_kernel<192, 1, 512, 1216, 1024><<<dim3(256, 8), 256, 0, stream>>>(x1, x2, x3, W7, s7, b7, c7, h7);
    gemm_kernel<512, 2, 256, 512, 0><<<dim3(256, 4), 256, 0, stream>>>(h7, nullptr, nullptr, W8, s8, b8, nullptr, h8);
    gemm_kernel<256, 3, 64, 256, 0><<<dim3(256, 1), 256, 0, stream>>>(h8, nullptr, nullptr, W9, nullptr, b9, nullptr, outp);
}

// Round 2
// 817.125 us; speedup vs baseline: 1.3326x; 1.3326x over previous
//
#include <hip/hip_runtime.h>

#define N_PTS 4096
#define KNBR 40
#define BATCH 4

typedef __attribute__((ext_vector_type(8))) short bf16x8;
typedef __attribute__((ext_vector_type(4))) float f32x4;

__device__ __forceinline__ float lrelu(float v) { return v > 0.0f ? v : 0.2f * v; }

__device__ __forceinline__ short bf16_rn(float f) {
    unsigned u = __float_as_uint(f);
    unsigned r = (u + 0x7FFFu + ((u >> 16) & 1u)) >> 16;
    return (short)r;
}
__device__ __forceinline__ float bf16f(short h) {
    return __uint_as_float(((unsigned)(unsigned short)h) << 16);
}

// ---------------- KNN: exact top-40 per row via binary search on ordered-uint space ----------------
__global__ __launch_bounds__(256) void knn_kernel(const float* __restrict__ x, int* __restrict__ idxo)
{
    const int t = threadIdx.x;
    const int pt = blockIdx.x;
    const int b = pt >> 12, n = pt & 4095;
    const float* xb = x + b * 3 * N_PTS;
    const int lane = t & 63, wv = t >> 6;

    __shared__ unsigned wcnt[2][4];
    __shared__ int wpos_s, tcnt_s;
    __shared__ int ties[64];

    const float c0 = xb[n], c1 = xb[N_PTS + n], c2 = xb[2 * N_PTS + n];
    const float cc = c0 * c0 + c1 * c1 + c2 * c2;

    unsigned ov[16];
#pragma unroll
    for (int j = 0; j < 16; ++j) {
        int m = t + j * 256;
        float a0 = xb[m], a1 = xb[N_PTS + m], a2 = xb[2 * N_PTS + m];
        float d = 2.0f * (c0 * a0 + c1 * a1 + c2 * a2) - cc - (a0 * a0 + a1 * a1 + a2 * a2);
        unsigned u = __float_as_uint(d);
        ov[j] = (u & 0x80000000u) ? ~u : (u | 0x80000000u);
    }
    if (t == 0) { wpos_s = 0; tcnt_s = 0; }

    unsigned lo = 0u, hi = 0xFFFFFFFFu;
    int it = 0;
    while (lo < hi) {
        unsigned span = hi - lo;
        unsigned mid = lo + (span >> 1) + (span & 1u);
        int c = 0;
#pragma unroll
        for (int j = 0; j < 16; ++j) c += (ov[j] >= mid) ? 1 : 0;
#pragma unroll
        for (int off = 32; off > 0; off >>= 1) c += __shfl_down(c, off, 64);
        int p = it & 1;
        if (lane == 0) wcnt[p][wv] = (unsigned)c;
        __syncthreads();
        unsigned tot = wcnt[p][0] + wcnt[p][1] + wcnt[p][2] + wcnt[p][3];
        if (tot >= (unsigned)KNBR) lo = mid; else hi = mid - 1u;
        ++it;
    }
    const unsigned vstar = lo;
    __syncthreads();
#pragma unroll
    for (int j = 0; j < 16; ++j) {
        int m = t + j * 256;
        if (ov[j] > vstar) {
            int p = atomicAdd(&wpos_s, 1);
            idxo[pt * KNBR + p] = m;
        } else if (ov[j] == vstar) {
            int q = atomicAdd(&tcnt_s, 1);
            if (q < 64) ties[q] = m;
        }
    }
    __syncthreads();
    if (t == 0) {
        int c1n = wpos_s;
        int R = KNBR - c1n;
        int tc = tcnt_s < 64 ? tcnt_s : 64;
        for (int r = 0; r < R; ++r) {
            int bi = 0, bm = 0x7FFFFFFF;
            for (int q = 0; q < tc; ++q) {
                if (ties[q] < bm) { bm = ties[q]; bi = q; }
            }
            ties[bi] = 0x7FFFFFFF;
            idxo[pt * KNBR + c1n + r] = bm;
        }
    }
}

// ---------------- Layer 1: gather + conv1(6->64) + conv2(64->64) + max over k, fused per point ----------------
__global__ __launch_bounds__(256) void layer1_kernel(const float* __restrict__ x, const int* __restrict__ idx,
    const float* __restrict__ W1, const float* __restrict__ s1, const float* __restrict__ b1,
    const float* __restrict__ W2, const float* __restrict__ s2, const float* __restrict__ b2,
    float* __restrict__ x1out)
{
    const int t = threadIdx.x;
    const int pt = blockIdx.x;
    const int b = pt >> 12, n = pt & 4095;
    const float* xb = x + b * 3 * N_PTS;

    __shared__ float w1s[384];
    __shared__ float s1s[64], b1s[64], ctrvs[64];
    __shared__ int idxs[KNBR];
    __shared__ float nbr[KNBR][4];
    __shared__ float As[64][44];
    __shared__ float Bs[64][68];
    __shared__ float red[16][64];

    if (t < KNBR) idxs[t] = idx[pt * KNBR + t];
    if (t < 64) { s1s[t] = s1[t]; b1s[t] = b1[t]; }
    if (t < 128) { w1s[t] = W1[t]; w1s[t + 128] = W1[t + 128]; w1s[t + 256] = W1[t + 256]; }
    const float c0 = xb[n], c1 = xb[N_PTS + n], c2 = xb[2 * N_PTS + n];
    __syncthreads();
    if (t < 120) { int k = t / 3, c = t % 3; nbr[k][c] = xb[c * N_PTS + idxs[k]]; }
    if (t < 64) {
        int o = t;
        ctrvs[o] = (w1s[o*6+3] - w1s[o*6+0]) * c0 + (w1s[o*6+4] - w1s[o*6+1]) * c1
                 + (w1s[o*6+5] - w1s[o*6+2]) * c2;
    }
    {
        int o = t >> 2, i4 = (t & 3) * 4;
#pragma unroll
        for (int r = 0; r < 4; ++r) {
            int i0 = i4 + r * 16;
            float4 wvv = *reinterpret_cast<const float4*>(&W2[o * 64 + i0]);
            Bs[i0 + 0][o] = wvv.x; Bs[i0 + 1][o] = wvv.y; Bs[i0 + 2][o] = wvv.z; Bs[i0 + 3][o] = wvv.w;
        }
    }
    __syncthreads();
#pragma unroll
    for (int r = 0; r < 10; ++r) {
        int e = r * 256 + t;
        int k = e >> 6, o = e & 63;
        float v = w1s[o*6+0] * nbr[k][0] + w1s[o*6+1] * nbr[k][1] + w1s[o*6+2] * nbr[k][2] + ctrvs[o];
        As[o][k] = lrelu(v * s1s[o] + b1s[o]);
    }
    __syncthreads();
    const int tm = t & 15, tn = t >> 4;
    if (tm < 10) {
        float acc[4][4] = {};
#pragma unroll 8
        for (int kk = 0; kk < 64; ++kk) {
            float4 a = *reinterpret_cast<const float4*>(&As[kk][tm * 4]);
            float4 b4 = *reinterpret_cast<const float4*>(&Bs[kk][tn * 4]);
            float av[4] = {a.x, a.y, a.z, a.w};
            float bv[4] = {b4.x, b4.y, b4.z, b4.w};
#pragma unroll
            for (int i = 0; i < 4; ++i)
#pragma unroll
                for (int j = 0; j < 4; ++j) acc[i][j] = fmaf(av[i], bv[j], acc[i][j]);
        }
#pragma unroll
        for (int j = 0; j < 4; ++j) {
            int o = tn * 4 + j;
            float sv = s2[o], bvv = b2[o];
            float mx = -1e30f;
#pragma unroll
            for (int i = 0; i < 4; ++i) mx = fmaxf(mx, lrelu(acc[i][j] * sv + bvv));
            red[tm][o] = mx;
        }
    }
    __syncthreads();
    if (t < 64) {
        float m = red[0][t];
#pragma unroll
        for (int q = 1; q < 10; ++q) m = fmaxf(m, red[q][t]);
        x1out[pt * 64 + t] = m;
    }
}

// ---------------- prep: convert edge-conv weights to bf16 hi/lo + ctr-weight transpose ----------------
__global__ __launch_bounds__(256) void prep_kernel(const float* __restrict__ W3, const float* __restrict__ W4,
    const float* __restrict__ W5,
    short* __restrict__ w3h, short* __restrict__ w3l,
    short* __restrict__ w4h, short* __restrict__ w4l,
    short* __restrict__ w5h, short* __restrict__ w5l,
    float* __restrict__ wdt3, float* __restrict__ wdt5)
{
    int e = blockIdx.x * 256 + threadIdx.x;   // 4096
    int o = e >> 6, i = e & 63;
    float a = W3[o * 128 + i];
    short h = bf16_rn(a);
    w3h[e] = h; w3l[e] = bf16_rn(a - bf16f(h));
    wdt3[i * 64 + o] = W3[o * 128 + 64 + i] - a;
    float c = W4[o * 64 + i];
    h = bf16_rn(c);
    w4h[e] = h; w4l[e] = bf16_rn(c - bf16f(h));
    float d = W5[o * 128 + i];
    h = bf16_rn(d);
    w5h[e] = h; w5l[e] = bf16_rn(d - bf16f(h));
    wdt5[i * 64 + o] = W5[o * 128 + 64 + i] - d;
}

// ---------------- Edge layers via MFMA (split-bf16), 2 points/block, M=80 ----------------
// out[k_nbr][o] = sum_i nbr[i]*Wa[o][i] + ctrv[p][o]; optional second conv 64->64; max over 40 nbrs.
template<int HAS2>
__global__ __launch_bounds__(256) void edge_mfma_kernel(const float* __restrict__ src, const int* __restrict__ idx,
    const short* __restrict__ wah, const short* __restrict__ wal, const float* __restrict__ wdt,
    const float* __restrict__ sa, const float* __restrict__ ba,
    const short* __restrict__ wbh, const short* __restrict__ wbl,
    const float* __restrict__ sb, const float* __restrict__ bb,
    float* __restrict__ xout)
{
    const int t = threadIdx.x;
    const int pt0 = blockIdx.x * 2;
    const int b = pt0 >> 12;
    const int lane = t & 63, w = t >> 6;
    const int cn = lane & 15, kg = lane >> 4;

    __shared__ int idxs[80];
    __shared__ float ctr1[2][64];
    __shared__ float ctrv[2][64];
    __shared__ float Abuf[5808];            // 23232 B
    short* A_hi = (short*)Abuf;             // [80][72]
    short* A_lo = A_hi + 80 * 72;
    float* red = Abuf;                      // [80][68] fp32, aliases A after final sync

    if (t < 80) idxs[t] = idx[pt0 * KNBR + t];
    if (t >= 128) { int p = (t >> 6) & 1; int i = t & 63; ctr1[p][i] = src[(pt0 + p) * 64 + i]; }
    __syncthreads();

    // B-fragments for conv A (held in registers; this wave's o-tile = w)
    bf16x8 bh[2], bl[2];
#pragma unroll
    for (int kc = 0; kc < 2; ++kc) {
        int off = (w * 16 + cn) * 64 + kc * 32 + kg * 8;
        bh[kc] = *(const bf16x8*)(wah + off);
        bl[kc] = *(const bf16x8*)(wal + off);
    }

    // gather neighbors + split-convert into LDS (A layout: row-major, stride 72 bf16 = 144 B)
    {
        const int r0 = t >> 4, c4 = (t & 15) * 4;
#pragma unroll
        for (int r = 0; r < 5; ++r) {
            int row = r * 16 + r0;
            const float4 v = *(const float4*)(src + (size_t)(b * N_PTS + idxs[row]) * 64 + c4);
            short4 h, l;
            h.x = bf16_rn(v.x); l.x = bf16_rn(v.x - bf16f(h.x));
            h.y = bf16_rn(v.y); l.y = bf16_rn(v.y - bf16f(h.y));
            h.z = bf16_rn(v.z); l.z = bf16_rn(v.z - bf16f(h.z));
            h.w = bf16_rn(v.w); l.w = bf16_rn(v.w - bf16f(h.w));
            *(short4*)(A_hi + row * 72 + c4) = h;
            *(short4*)(A_lo + row * 72 + c4) = l;
        }
    }
    // ctrv[p][o] = sum_i (Wa[o][64+i]-Wa[o][i]) * ctr[p][i]   (wdt is [i][o] fp32)
    if (t < 128) {
        int p = t >> 6, o = t & 63;
        float s = 0.0f;
#pragma unroll 8
        for (int i = 0; i < 64; ++i) s = fmaf(wdt[i * 64 + o], ctr1[p][i], s);
        ctrv[p][o] = s;
    }
    __syncthreads();

    // conv A: 5 m-tiles, K=64 (2 chunks), split-bf16 (3 MFMA per chunk)
    f32x4 acc[5];
#pragma unroll
    for (int mt = 0; mt < 5; ++mt) {
        f32x4 a = {0.f, 0.f, 0.f, 0.f};
#pragma unroll
        for (int kc = 0; kc < 2; ++kc) {
            int ao = (mt * 16 + cn) * 72 + kc * 32 + kg * 8;
            bf16x8 ah = *(const bf16x8*)(A_hi + ao);
            bf16x8 al = *(const bf16x8*)(A_lo + ao);
            a = __builtin_amdgcn_mfma_f32_16x16x32_bf16(al, bh[kc], a, 0, 0, 0);
            a = __builtin_amdgcn_mfma_f32_16x16x32_bf16(ah, bl[kc], a, 0, 0, 0);
            a = __builtin_amdgcn_mfma_f32_16x16x32_bf16(ah, bh[kc], a, 0, 0, 0);
        }
        acc[mt] = a;
    }

    const int o1 = w * 16 + cn;
    const float sA = sa[o1], bA = ba[o1];
    __syncthreads();   // everyone done reading A before overwrite

    if (HAS2) {
        // y1 -> LDS in A-operand layout (bf16 hi/lo)
#pragma unroll
        for (int mt = 0; mt < 5; ++mt) {
#pragma unroll
            for (int reg = 0; reg < 4; ++reg) {
                int row = mt * 16 + kg * 4 + reg;
                int p = row >= KNBR;
                float v = lrelu((acc[mt][reg] + ctrv[p][o1]) * sA + bA);
                short h = bf16_rn(v);
                A_hi[row * 72 + o1] = h;
                A_lo[row * 72 + o1] = bf16_rn(v - bf16f(h));
            }
        }
        __syncthreads();
#pragma unroll
        for (int kc = 0; kc < 2; ++kc) {
            int off = (w * 16 + cn) * 64 + kc * 32 + kg * 8;
            bh[kc] = *(const bf16x8*)(wbh + off);
            bl[kc] = *(const bf16x8*)(wbl + off);
        }
#pragma unroll
        for (int mt = 0; mt < 5; ++mt) {
            f32x4 a = {0.f, 0.f, 0.f, 0.f};
#pragma unroll
            for (int kc = 0; kc < 2; ++kc) {
                int ao = (mt * 16 + cn) * 72 + kc * 32 + kg * 8;
                bf16x8 ah = *(const bf16x8*)(A_hi + ao);
                bf16x8 al = *(const bf16x8*)(A_lo + ao);
                a = __builtin_amdgcn_mfma_f32_16x16x32_bf16(al, bh[kc], a, 0, 0, 0);
                a = __builtin_amdgcn_mfma_f32_16x16x32_bf16(ah, bl[kc], a, 0, 0, 0);
                a = __builtin_amdgcn_mfma_f32_16x16x32_bf16(ah, bh[kc], a, 0, 0, 0);
            }
            acc[mt] = a;
        }
        const float sB = sb[o1], bB = bb[o1];
        __syncthreads();   // everyone done reading y1 before red overwrite
#pragma unroll
        for (int mt = 0; mt < 5; ++mt) {
#pragma unroll
            for (int reg = 0; reg < 4; ++reg) {
                int row = mt * 16 + kg * 4 + reg;
                red[row * 68 + o1] = lrelu(acc[mt][reg] * sB + bB);
            }
        }
    } else {
#pragma unroll
        for (int mt = 0; mt < 5; ++mt) {
#pragma unroll
            for (int reg = 0; reg < 4; ++reg) {
                int row = mt * 16 + kg * 4 + reg;
                int p = row >= KNBR;
                red[row * 68 + o1] = lrelu((acc[mt][reg] + ctrv[p][o1]) * sA + bA);
            }
        }
    }
    __syncthreads();
    if (t < 128) {
        int p = t >> 6, o = t & 63;
        float m = -1e30f;
#pragma unroll 8
        for (int k = 0; k < KNBR; ++k) m = fmaxf(m, red[(p * KNBR + k) * 68 + o]);
        xout[(pt0 + p) * 64 + o] = m;
    }
}

// ---------------- Generic 64x64-tile GEMM with fused epilogues ----------------
template<int KD, int MODE, int NTOT, int LDB, int BOFF>
__global__ __launch_bounds__(256) void gemm_kernel(const float* __restrict__ A0, const float* __restrict__ A1,
    const float* __restrict__ A2, const float* __restrict__ Bw,
    const float* __restrict__ sv, const float* __restrict__ bv,
    const float* __restrict__ extra, float* __restrict__ outp)
{
    const int t = threadIdx.x;
    const int m0 = blockIdx.x * 64;
    const int n0 = blockIdx.y * 64;
    __shared__ float As[16][68];
    __shared__ float Bs[16][68];
    __shared__ float red[16][64];
    const int mrow = t >> 2, kq = (t & 3) * 4;
    const int tm = t & 15, tn = t >> 4;
    float acc[4][4] = {};
    for (int ks = 0; ks < KD; ks += 16) {
        float4 av;
        if (MODE == 0 || MODE == 1) {
            int k = ks + kq;
            const float* srcp = (k < 64) ? A0 : ((k < 128) ? A1 : A2);
            av = *reinterpret_cast<const float4*>(&srcp[(m0 + mrow) * 64 + (k & 63)]);
        } else {
            av = *reinterpret_cast<const float4*>(&A0[(m0 + mrow) * KD + ks + kq]);
        }
        As[kq+0][mrow] = av.x; As[kq+1][mrow] = av.y; As[kq+2][mrow] = av.z; As[kq+3][mrow] = av.w;
        float4 bw;
        {
            int o = n0 + mrow;
            if (MODE == 3 && o >= 63) bw = make_float4(0.f, 0.f, 0.f, 0.f);
            else bw = *reinterpret_cast<const float4*>(&Bw[o * LDB + BOFF + ks + kq]);
        }
        Bs[kq+0][mrow] = bw.x; Bs[kq+1][mrow] = bw.y; Bs[kq+2][mrow] = bw.z; Bs[kq+3][mrow] = bw.w;
        __syncthreads();
#pragma unroll
        for (int kk = 0; kk < 16; ++kk) {
            float4 a = *reinterpret_cast<const float4*>(&As[kk][tm * 4]);
            float4 b4 = *reinterpret_cast<const float4*>(&Bs[kk][tn * 4]);
            float avr[4] = {a.x,a.y,a.z,a.w}, bvr[4] = {b4.x,b4.y,b4.z,b4.w};
#pragma unroll
            for (int i = 0; i < 4; ++i)
#pragma unroll
                for (int j = 0; j < 4; ++j) acc[i][j] = fmaf(avr[i], bvr[j], acc[i][j]);
        }
        __syncthreads();
    }
    if (MODE == 0) {
#pragma unroll
        for (int j = 0; j < 4; ++j) {
            int o = n0 + tn * 4 + j;
            float s = sv[o], bbv = bv[o];
            float m = -1e30f;
#pragma unroll
            for (int i = 0; i < 4; ++i) m = fmaxf(m, lrelu(acc[i][j] * s + bbv));
            red[tm][tn * 4 + j] = m;
        }
        __syncthreads();
        if (t < 64) {
            float m = red[0][t];
#pragma unroll
            for (int q = 1; q < 16; ++q) m = fmaxf(m, red[q][t]);
            outp[blockIdx.x * NTOT + n0 + t] = m;
        }
    } else if (MODE == 1) {
        const int bidx = m0 >> 12;
#pragma unroll
        for (int i = 0; i < 4; ++i) {
            float4 w;
            float* wp = &w.x;
#pragma unroll
            for (int j = 0; j < 4; ++j) {
                int o = n0 + tn * 4 + j;
                wp[j] = lrelu((acc[i][j] + extra[bidx * 512 + o]) * sv[o] + bv[o]);
            }
            *reinterpret_cast<float4*>(&outp[(m0 + tm * 4 + i) * NTOT + n0 + tn * 4]) = w;
        }
    } else if (MODE == 2) {
#pragma unroll
        for (int i = 0; i < 4; ++i) {
            float4 w;
            float* wp = &w.x;
#pragma unroll
            for (int j = 0; j < 4; ++j) {
                int o = n0 + tn * 4 + j;
                wp[j] = lrelu(acc[i][j] * sv[o] + bv[o]);
            }
            *reinterpret_cast<float4*>(&outp[(m0 + tm * 4 + i) * NTOT + n0 + tn * 4]) = w;
        }
    } else {
        const int bidx = m0 >> 12;
        const int nb = m0 & 4095;
#pragma unroll
        for (int j = 0; j < 4; ++j) {
            int o = tn * 4 + j;
            if (o < 63) {
                float b9v = bv[o];
                float4 w;
                w.x = acc[0][j] + b9v; w.y = acc[1][j] + b9v; w.z = acc[2][j] + b9v; w.w = acc[3][j] + b9v;
                *reinterpret_cast<float4*>(&outp[(bidx * 63 + o) * N_PTS + nb + tm * 4]) = w;
            }
        }
    }
}

__global__ __launch_bounds__(256) void greduce_kernel(const float* __restrict__ gpart, float* __restrict__ g)
{
    int tid = blockIdx.x * 256 + threadIdx.x;   // 4096
    int b = tid >> 10, o = tid & 1023;
    float m = -1e30f;
    for (int q = 0; q < 64; ++q) m = fmaxf(m, gpart[(b * 64 + q) * 1024 + o]);
    g[tid] = m;
}

__global__ __launch_bounds__(256) void c7_kernel(const float* __restrict__ g, const float* __restrict__ W7,
                                                 float* __restrict__ c7)
{
    int tid = blockIdx.x * 256 + threadIdx.x;   // 2048
    int b = tid >> 9, o = tid & 511;
    const float* gb = g + b * 1024;
    const float* wr = W7 + o * 1216;
    float s = 0.0f;
    for (int i = 0; i < 1024; i += 4) {
        float4 wv4 = *reinterpret_cast<const float4*>(&wr[i]);
        float4 gv4 = *reinterpret_cast<const float4*>(&gb[i]);
        s += wv4.x * gv4.x + wv4.y * gv4.y + wv4.z * gv4.z + wv4.w * gv4.w;
    }
    c7[tid] = s;
}

extern "C" void kernel_launch(void* const* d_in, const int* in_sizes, int n_in,
                              void* d_out, int out_size, void* d_ws, size_t ws_size,
                              hipStream_t stream)
{
    const float* x  = (const float*)d_in[0];
    const float* W1 = (const float*)d_in[1];
    const float* s1 = (const float*)d_in[2];
    const float* b1 = (const float*)d_in[3];
    const float* W2 = (const float*)d_in[4];
    const float* s2 = (const float*)d_in[5];
    const float* b2 = (const float*)d_in[6];
    const float* W3 = (const float*)d_in[7];
    const float* s3 = (const float*)d_in[8];
    const float* b3 = (const float*)d_in[9];
    const float* W4 = (const float*)d_in[10];
    const float* s4 = (const float*)d_in[11];
    const float* b4 = (const float*)d_in[12];
    const float* W5 = (const float*)d_in[13];
    const float* s5 = (const float*)d_in[14];
    const float* b5 = (const float*)d_in[15];
    const float* W6 = (const float*)d_in[16];
    const float* s6 = (const float*)d_in[17];
    const float* b6 = (const float*)d_in[18];
    const float* W7 = (const float*)d_in[19];
    const float* s7 = (const float*)d_in[20];
    const float* b7 = (const float*)d_in[21];
    const float* W8 = (const float*)d_in[22];
    const float* s8 = (const float*)d_in[23];
    const float* b8 = (const float*)d_in[24];
    const float* W9 = (const float*)d_in[25];
    const float* b9 = (const float*)d_in[26];

    char* ws = (char*)d_ws;
    int*   idx   = (int*)(ws);                       // 2.62 MB
    float* x1    = (float*)(ws + 2621440);           // 4.19 MB
    float* x2    = (float*)(ws + 6815744);
    float* x3    = (float*)(ws + 11010048);
    float* gpart = (float*)(ws + 15204352);
    float* g     = (float*)(ws + 16252928);
    float* c7    = (float*)(ws + 16269312);
    float* h7    = (float*)(ws + 16277504);          // 33.6 MB
    float* h8    = (float*)(ws + 49831936);          // 16.8 MB  -> end 66609152
    short* w3h   = (short*)(ws + 66609152);
    short* w3l   = w3h + 4096;
    short* w4h   = w3h + 8192;
    short* w4l   = w3h + 12288;
    short* w5h   = w3h + 16384;
    short* w5l   = w3h + 20480;
    float* wdt3  = (float*)(ws + 66609152 + 49152);
    float* wdt5  = wdt3 + 4096;
    float* outp  = (float*)d_out;

    knn_kernel<<<BATCH * N_PTS, 256, 0, stream>>>(x, idx);
    prep_kernel<<<16, 256, 0, stream>>>(W3, W4, W5, w3h, w3l, w4h, w4l, w5h, w5l, wdt3, wdt5);
    layer1_kernel<<<BATCH * N_PTS, 256, 0, stream>>>(x, idx, W1, s1, b1, W2, s2, b2, x1);
    edge_mfma_kernel<1><<<BATCH * N_PTS / 2, 256, 0, stream>>>(x1, idx, w3h, w3l, wdt3, s3, b3, w4h, w4l, s4, b4, x2);
    edge_mfma_kernel<0><<<BATCH * N_PTS / 2, 256, 0, stream>>>(x2, idx, w5h, w5l, wdt5, s5, b5, nullptr, nullptr, nullptr, nullptr, x3);
    gemm_kernel<192, 0, 1024, 192, 0><<<dim3(256, 16), 256, 0, stream>>>(x1, x2, x3, W6, s6, b6, nullptr, gpart);
    greduce_kernel<<<16, 256, 0, stream>>>(gpart, g);
    c7_kernel<<<8, 256, 0, stream>>>(g, W7, c7);
    gemm_kernel<192, 1, 512, 1216, 1024><<<dim3(256, 8), 256, 0, stream>>>(x1, x2, x3, W7, s7, b7, c7, h7);
    gemm_kernel<512, 2, 256, 512, 0><<<dim3(256, 4), 256, 0, stream>>>(h7, nullptr, nullptr, W8, s8, b8, nullptr, h8);
    gemm_kernel<256, 3, 64, 256, 0><<<dim3(256, 1), 256, 0, stream>>>(h8, nullptr, nullptr, W9, nullptr, b9, nullptr, outp);
}

// Round 4
// 584.390 us; speedup vs baseline: 1.8633x; 1.3983x over previous
//
#include <hip/hip_runtime.h>

#define N_PTS 4096
#define KNBR 40
#define BATCH 4

typedef __attribute__((ext_vector_type(8))) short bf16x8;
typedef __attribute__((ext_vector_type(4))) float f32x4;

__device__ __forceinline__ float lrelu(float v) { return v > 0.0f ? v : 0.2f * v; }

__device__ __forceinline__ short bf16_rn(float f) {
    unsigned u = __float_as_uint(f);
    unsigned r = (u + 0x7FFFu + ((u >> 16) & 1u)) >> 16;
    return (short)r;
}
__device__ __forceinline__ float bf16f(short h) {
    return __uint_as_float(((unsigned)(unsigned short)h) << 16);
}
__device__ __forceinline__ unsigned packbf(float v) {
    short h = bf16_rn(v);
    float r = v - bf16f(h);
    short l = bf16_rn(r);
    return (((unsigned)(unsigned short)h) << 16) | (unsigned)(unsigned short)l;
}

// ---------------- KNN: exact top-40 via two-level radix select on ordered-uint keys ----------------
__global__ __launch_bounds__(256) void knn_kernel(const float* __restrict__ x, int* __restrict__ idxo)
{
    const int t = threadIdx.x;
    const int pt = blockIdx.x;
    const int b = pt >> 12, n = pt & 4095;
    const float* xb = x + b * 3 * N_PTS;
    const int lane = t & 63, wv = t >> 6;

    __shared__ unsigned hist[4096];
    __shared__ unsigned wtot[4];
    __shared__ int sh[8];          // 0:B1 1:nAbove1 2:needRef 3:emitPos 4:B2 5:nAbove2 6:candCnt 7:R(target)
    __shared__ unsigned cov[128];
    __shared__ int cidx[128];

    const float c0 = xb[n], c1 = xb[N_PTS + n], c2 = xb[2 * N_PTS + n];
    const float cc = c0 * c0 + c1 * c1 + c2 * c2;

    unsigned ov[16];
#pragma unroll
    for (int j = 0; j < 16; ++j) {
        int m = t + j * 256;
        float a0 = xb[m], a1 = xb[N_PTS + m], a2 = xb[2 * N_PTS + m];
        float d = 2.0f * (c0 * a0 + c1 * a1 + c2 * a2) - cc - (a0 * a0 + a1 * a1 + a2 * a2);
        unsigned u = __float_as_uint(d);
        ov[j] = (u & 0x80000000u) ? ~u : (u | 0x80000000u);
    }

#pragma unroll
    for (int j = 0; j < 16; ++j) hist[t + j * 256] = 0;
    if (t < 8) sh[t] = 0;
    __syncthreads();
#pragma unroll
    for (int j = 0; j < 16; ++j) atomicAdd(&hist[ov[j] >> 20], 1u);
    __syncthreads();

    // ---- level 1 select: chunk sums + suffix scan (chunk t = bins [16t,16t+16)) ----
    unsigned cs = 0;
#pragma unroll
    for (int q = 0; q < 16; ++q) cs += hist[t * 16 + q];
    unsigned val = cs;
#pragma unroll
    for (int off = 1; off < 64; off <<= 1) {
        unsigned o = __shfl_down(val, off, 64);
        if (lane + off < 64) val += o;
    }
    if (lane == 0) wtot[wv] = val;
    __syncthreads();
    unsigned above_w = 0;
    for (int q = wv + 1; q < 4; ++q) above_w += wtot[q];
    unsigned Sincl = val + above_w;
    unsigned excl = Sincl - cs;
    if (excl < KNBR && Sincl >= KNBR) { sh[0] = t; sh[1] = (int)excl; }
    __syncthreads();
    if (t == 0) {
        int tstar = sh[0];
        unsigned run = (unsigned)sh[1];
        int B1 = -1; unsigned nab = 0;
        for (int q = 15; q >= 0; --q) {
            int bb = tstar * 16 + q;
            unsigned h = hist[bb];
            if (run + h >= KNBR) { B1 = bb; nab = run; break; }
            run += h;
        }
        sh[0] = B1; sh[1] = (int)nab;
        int R1 = KNBR - (int)nab;
        sh[7] = R1;
        sh[2] = ((int)hist[B1] > R1) ? 1 : 0;   // need refinement?
    }
    __syncthreads();
    const unsigned B1 = (unsigned)sh[0];
    const int needRef = sh[2];
    const int R1 = sh[7];

    // emit strictly-above-bin values
#pragma unroll
    for (int j = 0; j < 16; ++j) {
        unsigned bb = ov[j] >> 20;
        if (bb > B1) { int p = atomicAdd(&sh[3], 1); idxo[pt * KNBR + p] = t + j * 256; }
        else if (bb == B1 && !needRef) { int p = atomicAdd(&sh[3], 1); idxo[pt * KNBR + p] = t + j * 256; }
    }
    if (!needRef) return;

    // ---- level 2: refine within bin B1 on bits [19:8] ----
    __syncthreads();
#pragma unroll
    for (int j = 0; j < 16; ++j) hist[t + j * 256] = 0;
    __syncthreads();
#pragma unroll
    for (int j = 0; j < 16; ++j)
        if ((ov[j] >> 20) == B1) atomicAdd(&hist[(ov[j] >> 8) & 0xFFFu], 1u);
    __syncthreads();
    cs = 0;
#pragma unroll
    for (int q = 0; q < 16; ++q) cs += hist[t * 16 + q];
    val = cs;
#pragma unroll
    for (int off = 1; off < 64; off <<= 1) {
        unsigned o = __shfl_down(val, off, 64);
        if (lane + off < 64) val += o;
    }
    if (lane == 0) wtot[wv] = val;
    __syncthreads();
    above_w = 0;
    for (int q = wv + 1; q < 4; ++q) above_w += wtot[q];
    Sincl = val + above_w;
    excl = Sincl - cs;
    if ((int)excl < R1 && (int)Sincl >= R1) { sh[4] = t; sh[5] = (int)excl; }
    __syncthreads();
    if (t == 0) {
        int tstar = sh[4];
        unsigned run = (unsigned)sh[5];
        int B2 = -1; unsigned nab = 0;
        for (int q = 15; q >= 0; --q) {
            int bb = tstar * 16 + q;
            unsigned h = hist[bb];
            if ((int)(run + h) >= R1) { B2 = bb; nab = run; break; }
            run += h;
        }
        sh[4] = B2; sh[5] = (int)nab;
        sh[2] = ((int)hist[B2] > (R1 - (int)nab)) ? 1 : 0;  // exact fit?
        sh[6] = 0;
    }
    __syncthreads();
    const unsigned B2 = (unsigned)sh[4];
    const int R2 = R1 - sh[5];
    const int needSer = sh[2];
#pragma unroll
    for (int j = 0; j < 16; ++j) {
        if ((ov[j] >> 20) == B1) {
            unsigned b2 = (ov[j] >> 8) & 0xFFFu;
            if (b2 > B2) { int p = atomicAdd(&sh[3], 1); idxo[pt * KNBR + p] = t + j * 256; }
            else if (b2 == B2) {
                if (!needSer) { int p = atomicAdd(&sh[3], 1); idxo[pt * KNBR + p] = t + j * 256; }
                else { int q = atomicAdd(&sh[6], 1); if (q < 128) { cov[q] = ov[j]; cidx[q] = t + j * 256; } }
            }
        }
    }
    if (!needSer) return;
    __syncthreads();
    if (t == 0) {
        int tc = sh[6] < 128 ? sh[6] : 128;
        int pos = sh[3];
        for (int r = 0; r < R2; ++r) {
            unsigned bestv = 0; int besti = 0x7FFFFFFF; int bestq = -1;
            for (int q = 0; q < tc; ++q) {
                if (cidx[q] < 0) continue;
                if (bestq < 0 || cov[q] > bestv || (cov[q] == bestv && cidx[q] < besti)) {
                    bestv = cov[q]; besti = cidx[q]; bestq = q;
                }
            }
            idxo[pt * KNBR + pos + r] = besti;
            cidx[bestq] = -1;
        }
    }
}

// ---------------- Layer 1: gather + conv1(6->64) + conv2(64->64) + max over k, fused per point ----------------
__global__ __launch_bounds__(256) void layer1_kernel(const float* __restrict__ x, const int* __restrict__ idx,
    const float* __restrict__ W1, const float* __restrict__ s1, const float* __restrict__ b1,
    const float* __restrict__ W2, const float* __restrict__ s2, const float* __restrict__ b2,
    float* __restrict__ x1out, unsigned* __restrict__ x1p)
{
    const int t = threadIdx.x;
    const int pt = blockIdx.x;
    const int b = pt >> 12, n = pt & 4095;
    const float* xb = x + b * 3 * N_PTS;

    __shared__ float w1s[384];
    __shared__ float s1s[64], b1s[64], ctrvs[64];
    __shared__ int idxs[KNBR];
    __shared__ float nbr[KNBR][4];
    __shared__ float As[64][44];
    __shared__ float Bs[64][68];
    __shared__ float red[16][64];

    if (t < KNBR) idxs[t] = idx[pt * KNBR + t];
    if (t < 64) { s1s[t] = s1[t]; b1s[t] = b1[t]; }
    if (t < 128) { w1s[t] = W1[t]; w1s[t + 128] = W1[t + 128]; w1s[t + 256] = W1[t + 256]; }
    const float c0 = xb[n], c1 = xb[N_PTS + n], c2 = xb[2 * N_PTS + n];
    __syncthreads();
    if (t < 120) { int k = t / 3, c = t % 3; nbr[k][c] = xb[c * N_PTS + idxs[k]]; }
    if (t < 64) {
        int o = t;
        ctrvs[o] = (w1s[o*6+3] - w1s[o*6+0]) * c0 + (w1s[o*6+4] - w1s[o*6+1]) * c1
                 + (w1s[o*6+5] - w1s[o*6+2]) * c2;
    }
    {
        int o = t >> 2, i4 = (t & 3) * 4;
#pragma unroll
        for (int r = 0; r < 4; ++r) {
            int i0 = i4 + r * 16;
            float4 wvv = *reinterpret_cast<const float4*>(&W2[o * 64 + i0]);
            Bs[i0 + 0][o] = wvv.x; Bs[i0 + 1][o] = wvv.y; Bs[i0 + 2][o] = wvv.z; Bs[i0 + 3][o] = wvv.w;
        }
    }
    __syncthreads();
#pragma unroll
    for (int r = 0; r < 10; ++r) {
        int e = r * 256 + t;
        int k = e >> 6, o = e & 63;
        float v = w1s[o*6+0] * nbr[k][0] + w1s[o*6+1] * nbr[k][1] + w1s[o*6+2] * nbr[k][2] + ctrvs[o];
        As[o][k] = lrelu(v * s1s[o] + b1s[o]);
    }
    __syncthreads();
    const int tm = t & 15, tn = t >> 4;
    if (tm < 10) {
        float acc[4][4] = {};
#pragma unroll 8
        for (int kk = 0; kk < 64; ++kk) {
            float4 a = *reinterpret_cast<const float4*>(&As[kk][tm * 4]);
            float4 b4 = *reinterpret_cast<const float4*>(&Bs[kk][tn * 4]);
            float av[4] = {a.x, a.y, a.z, a.w};
            float bv[4] = {b4.x, b4.y, b4.z, b4.w};
#pragma unroll
            for (int i = 0; i < 4; ++i)
#pragma unroll
                for (int j = 0; j < 4; ++j) acc[i][j] = fmaf(av[i], bv[j], acc[i][j]);
        }
#pragma unroll
        for (int j = 0; j < 4; ++j) {
            int o = tn * 4 + j;
            float sv = s2[o], bvv = b2[o];
            float mx = -1e30f;
#pragma unroll
            for (int i = 0; i < 4; ++i) mx = fmaxf(mx, lrelu(acc[i][j] * sv + bvv));
            red[tm][o] = mx;
        }
    }
    __syncthreads();
    if (t < 64) {
        float m = red[0][t];
#pragma unroll
        for (int q = 1; q < 10; ++q) m = fmaxf(m, red[q][t]);
        x1out[pt * 64 + t] = m;
        x1p[pt * 64 + t] = packbf(m);
    }
}

// ---------------- prep: edge-conv weights -> bf16 hi/lo + ctr-weight transpose ----------------
__global__ __launch_bounds__(256) void prep_kernel(const float* __restrict__ W3, const float* __restrict__ W4,
    const float* __restrict__ W5,
    short* __restrict__ w3h, short* __restrict__ w3l,
    short* __restrict__ w4h, short* __restrict__ w4l,
    short* __restrict__ w5h, short* __restrict__ w5l,
    float* __restrict__ wdt3, float* __restrict__ wdt5)
{
    int e = blockIdx.x * 256 + threadIdx.x;   // 4096
    int o = e >> 6, i = e & 63;
    float a = W3[o * 128 + i];
    short h = bf16_rn(a);
    w3h[e] = h; w3l[e] = bf16_rn(a - bf16f(h));
    wdt3[i * 64 + o] = W3[o * 128 + 64 + i] - a;
    float c = W4[o * 64 + i];
    h = bf16_rn(c);
    w4h[e] = h; w4l[e] = bf16_rn(c - bf16f(h));
    float d = W5[o * 128 + i];
    h = bf16_rn(d);
    w5h[e] = h; w5l[e] = bf16_rn(d - bf16f(h));
    wdt5[i * 64 + o] = W5[o * 128 + 64 + i] - d;
}

// ---------------- prep2: W6/W7(slice)/W8/W9 -> split bf16 hi/lo ----------------
__global__ __launch_bounds__(256) void prep2_kernel(const float* __restrict__ W6, const float* __restrict__ W7,
    const float* __restrict__ W8, const float* __restrict__ W9,
    short* __restrict__ w6h, short* __restrict__ w6l,
    short* __restrict__ w7h, short* __restrict__ w7l,
    short* __restrict__ w8h, short* __restrict__ w8l,
    short* __restrict__ w9h, short* __restrict__ w9l)
{
    int e = blockIdx.x * 256 + threadIdx.x;
    float v; short* dh; short* dl; int di;
    if (e < 196608) {                       // W6: 1024x192
        v = W6[e]; dh = w6h; dl = w6l; di = e;
    } else if (e < 294912) {                // W7 cols 1024..1215: 512x192
        int ee = e - 196608;
        int o = ee / 192, k = ee - o * 192;
        v = W7[o * 1216 + 1024 + k]; dh = w7h; dl = w7l; di = ee;
    } else if (e < 425984) {                // W8: 256x512
        int ee = e - 294912;
        v = W8[ee]; dh = w8h; dl = w8l; di = ee;
    } else if (e < 442368) {                // W9: 64x256 (row 63 zero-pad)
        int ee = e - 425984;
        int o = ee >> 8, k = ee & 255;
        v = (o < 63) ? W9[o * 256 + k] : 0.0f;
        dh = w9h; dl = w9l; di = ee;
    } else return;
    short h = bf16_rn(v);
    dh[di] = h; dl[di] = bf16_rn(v - bf16f(h));
}

// ---------------- Edge layers via MFMA (split-bf16), 2 points/block, M=80 ----------------
template<int HAS2>
__global__ __launch_bounds__(256) void edge_mfma_kernel(const float* __restrict__ src, const int* __restrict__ idx,
    const short* __restrict__ wah, const short* __restrict__ wal, const float* __restrict__ wdt,
    const float* __restrict__ sa, const float* __restrict__ ba,
    const short* __restrict__ wbh, const short* __restrict__ wbl,
    const float* __restrict__ sb, const float* __restrict__ bb,
    float* __restrict__ xout, unsigned* __restrict__ xpout)
{
    const int t = threadIdx.x;
    const int pt0 = blockIdx.x * 2;
    const int b = pt0 >> 12;
    const int lane = t & 63, w = t >> 6;
    const int cn = lane & 15, kg = lane >> 4;

    __shared__ int idxs[80];
    __shared__ float ctr1[2][64];
    __shared__ float ctrv[2][64];
    __shared__ float Abuf[5808];
    short* A_hi = (short*)Abuf;
    short* A_lo = A_hi + 80 * 72;
    float* red = Abuf;

    if (t < 80) idxs[t] = idx[pt0 * KNBR + t];
    if (t >= 128) { int p = (t >> 6) & 1; int i = t & 63; ctr1[p][i] = src[(pt0 + p) * 64 + i]; }
    __syncthreads();

    bf16x8 bh[2], bl[2];
#pragma unroll
    for (int kc = 0; kc < 2; ++kc) {
        int off = (w * 16 + cn) * 64 + kc * 32 + kg * 8;
        bh[kc] = *(const bf16x8*)(wah + off);
        bl[kc] = *(const bf16x8*)(wal + off);
    }

    {
        const int r0 = t >> 4, c4 = (t & 15) * 4;
#pragma unroll
        for (int r = 0; r < 5; ++r) {
            int row = r * 16 + r0;
            const float4 v = *(const float4*)(src + (size_t)(b * N_PTS + idxs[row]) * 64 + c4);
            short4 h, l;
            h.x = bf16_rn(v.x); l.x = bf16_rn(v.x - bf16f(h.x));
            h.y = bf16_rn(v.y); l.y = bf16_rn(v.y - bf16f(h.y));
            h.z = bf16_rn(v.z); l.z = bf16_rn(v.z - bf16f(h.z));
            h.w = bf16_rn(v.w); l.w = bf16_rn(v.w - bf16f(h.w));
            *(short4*)(A_hi + row * 72 + c4) = h;
            *(short4*)(A_lo + row * 72 + c4) = l;
        }
    }
    if (t < 128) {
        int p = t >> 6, o = t & 63;
        float s = 0.0f;
#pragma unroll 8
        for (int i = 0; i < 64; ++i) s = fmaf(wdt[i * 64 + o], ctr1[p][i], s);
        ctrv[p][o] = s;
    }
    __syncthreads();

    f32x4 acc[5];
#pragma unroll
    for (int mt = 0; mt < 5; ++mt) {
        f32x4 a = {0.f, 0.f, 0.f, 0.f};
#pragma unroll
        for (int kc = 0; kc < 2; ++kc) {
            int ao = (mt * 16 + cn) * 72 + kc * 32 + kg * 8;
            bf16x8 ah = *(const bf16x8*)(A_hi + ao);
            bf16x8 al = *(const bf16x8*)(A_lo + ao);
            a = __builtin_amdgcn_mfma_f32_16x16x32_bf16(al, bh[kc], a, 0, 0, 0);
            a = __builtin_amdgcn_mfma_f32_16x16x32_bf16(ah, bl[kc], a, 0, 0, 0);
            a = __builtin_amdgcn_mfma_f32_16x16x32_bf16(ah, bh[kc], a, 0, 0, 0);
        }
        acc[mt] = a;
    }

    const int o1 = w * 16 + cn;
    const float sA = sa[o1], bA = ba[o1];
    __syncthreads();

    if (HAS2) {
#pragma unroll
        for (int mt = 0; mt < 5; ++mt) {
#pragma unroll
            for (int reg = 0; reg < 4; ++reg) {
                int row = mt * 16 + kg * 4 + reg;
                int p = row >= KNBR;
                float v = lrelu((acc[mt][reg] + ctrv[p][o1]) * sA + bA);
                short h = bf16_rn(v);
                A_hi[row * 72 + o1] = h;
                A_lo[row * 72 + o1] = bf16_rn(v - bf16f(h));
            }
        }
        __syncthreads();
#pragma unroll
        for (int kc = 0; kc < 2; ++kc) {
            int off = (w * 16 + cn) * 64 + kc * 32 + kg * 8;
            bh[kc] = *(const bf16x8*)(wbh + off);
            bl[kc] = *(const bf16x8*)(wbl + off);
        }
#pragma unroll
        for (int mt = 0; mt < 5; ++mt) {
            f32x4 a = {0.f, 0.f, 0.f, 0.f};
#pragma unroll
            for (int kc = 0; kc < 2; ++kc) {
                int ao = (mt * 16 + cn) * 72 + kc * 32 + kg * 8;
                bf16x8 ah = *(const bf16x8*)(A_hi + ao);
                bf16x8 al = *(const bf16x8*)(A_lo + ao);
                a = __builtin_amdgcn_mfma_f32_16x16x32_bf16(al, bh[kc], a, 0, 0, 0);
                a = __builtin_amdgcn_mfma_f32_16x16x32_bf16(ah, bl[kc], a, 0, 0, 0);
                a = __builtin_amdgcn_mfma_f32_16x16x32_bf16(ah, bh[kc], a, 0, 0, 0);
            }
            acc[mt] = a;
        }
        const float sB = sb[o1], bB = bb[o1];
        __syncthreads();
#pragma unroll
        for (int mt = 0; mt < 5; ++mt) {
#pragma unroll
            for (int reg = 0; reg < 4; ++reg) {
                int row = mt * 16 + kg * 4 + reg;
                red[row * 68 + o1] = lrelu(acc[mt][reg] * sB + bB);
            }
        }
    } else {
#pragma unroll
        for (int mt = 0; mt < 5; ++mt) {
#pragma unroll
            for (int reg = 0; reg < 4; ++reg) {
                int row = mt * 16 + kg * 4 + reg;
                int p = row >= KNBR;
                red[row * 68 + o1] = lrelu((acc[mt][reg] + ctrv[p][o1]) * sA + bA);
            }
        }
    }
    __syncthreads();
    if (t < 128) {
        int p = t >> 6, o = t & 63;
        float m = -1e30f;
#pragma unroll 8
        for (int k = 0; k < KNBR; ++k) m = fmaxf(m, red[(p * KNBR + k) * 68 + o]);
        xout[(pt0 + p) * 64 + o] = m;
        xpout[(pt0 + p) * 64 + o] = packbf(m);
    }
}

// ---------------- Split-bf16 MFMA GEMM, fused epilogues ----------------
// MODE 0: conv6 (A=x123p K=192, lrelu, per-block col-max -> gpart)
// MODE 3: conv9 (A=h8p K=256, +b9, transposed fp32 store, col<63)
template<int MODE, int MT, int NT, int KD, int NTOT>
__global__ __launch_bounds__(256) void gemm_mfma(
    const unsigned* __restrict__ A0, const unsigned* __restrict__ A1, const unsigned* __restrict__ A2,
    const short* __restrict__ Bh, const short* __restrict__ Bl,
    const float* __restrict__ sv, const float* __restrict__ bvv,
    const float* __restrict__ extra, void* __restrict__ outp)
{
    const int t = threadIdx.x;
    const int w = t >> 6, lane = t & 63;
    const int cn = lane & 15, kg = lane >> 4;
    const int m0 = blockIdx.x * (MT * 16);
    const int n0 = blockIdx.y * (NT * 64);

    __shared__ __align__(16) short Abuf2[2 * MT * 16 * 40];
    short* A_hi = Abuf2;
    short* A_lo = Abuf2 + MT * 16 * 40;

    f32x4 acc[MT][NT];
#pragma unroll
    for (int mt = 0; mt < MT; ++mt)
#pragma unroll
        for (int nt = 0; nt < NT; ++nt) acc[mt][nt] = (f32x4){0.f, 0.f, 0.f, 0.f};

    for (int kc = 0; kc < KD / 32; ++kc) {
        // stage A k-chunk (32) into LDS hi/lo planes
        {
            const int kq = (t & 7) * 4;
            const int r0 = t >> 3;
#pragma unroll
            for (int rr = 0; rr < (MT * 16) / 32; ++rr) {
                int row = r0 + rr * 32;
                int gk = kc * 32 + kq;
                uint4 v;
                if (MODE == 0) {
                    const unsigned* srcp = (gk < 64) ? A0 : ((gk < 128) ? A1 : A2);
                    v = *(const uint4*)(srcp + (size_t)(m0 + row) * 64 + (gk & 63));
                } else {
                    v = *(const uint4*)(A0 + (size_t)(m0 + row) * KD + gk);
                }
                short4 h, l;
                h.x = (short)(v.x >> 16); l.x = (short)v.x;
                h.y = (short)(v.y >> 16); l.y = (short)v.y;
                h.z = (short)(v.z >> 16); l.z = (short)v.z;
                h.w = (short)(v.w >> 16); l.w = (short)v.w;
                *(short4*)(A_hi + row * 40 + kq) = h;
                *(short4*)(A_lo + row * 40 + kq) = l;
            }
        }
        __syncthreads();
        bf16x8 bh[NT], bl[NT];
#pragma unroll
        for (int nt = 0; nt < NT; ++nt) {
            int col = n0 + (w * NT + nt) * 16 + cn;
            int boff = col * KD + kc * 32 + kg * 8;
            bh[nt] = *(const bf16x8*)(Bh + boff);
            bl[nt] = *(const bf16x8*)(Bl + boff);
        }
#pragma unroll
        for (int mt = 0; mt < MT; ++mt) {
            int ao = (mt * 16 + cn) * 40 + kg * 8;
            bf16x8 ah = *(const bf16x8*)(A_hi + ao);
            bf16x8 al = *(const bf16x8*)(A_lo + ao);
#pragma unroll
            for (int nt = 0; nt < NT; ++nt) {
                acc[mt][nt] = __builtin_amdgcn_mfma_f32_16x16x32_bf16(al, bh[nt], acc[mt][nt], 0, 0, 0);
                acc[mt][nt] = __builtin_amdgcn_mfma_f32_16x16x32_bf16(ah, bl[nt], acc[mt][nt], 0, 0, 0);
                acc[mt][nt] = __builtin_amdgcn_mfma_f32_16x16x32_bf16(ah, bh[nt], acc[mt][nt], 0, 0, 0);
            }
        }
        __syncthreads();
    }

    if (MODE == 0) {
        float* gp = (float*)outp;
#pragma unroll
        for (int nt = 0; nt < NT; ++nt) {
            int col = n0 + (w * NT + nt) * 16 + cn;
            float s = sv[col], bb = bvv[col];
            float mx = -1e30f;
#pragma unroll
            for (int mt = 0; mt < MT; ++mt)
#pragma unroll
                for (int r = 0; r < 4; ++r) mx = fmaxf(mx, lrelu(acc[mt][nt][r] * s + bb));
            mx = fmaxf(mx, __shfl_xor(mx, 16, 64));
            mx = fmaxf(mx, __shfl_xor(mx, 32, 64));
            if (kg == 0) gp[blockIdx.x * NTOT + col] = mx;
        }
    } else {
        float* of = (float*)outp;
        const int b = m0 >> 12;
        const int nrow0 = m0 & 4095;
        int col = w * 16 + cn;
        if (col < 63) {
            float bb = bvv[col];
#pragma unroll
            for (int mt = 0; mt < MT; ++mt) {
                float4 o4;
                o4.x = acc[mt][0][0] + bb; o4.y = acc[mt][0][1] + bb;
                o4.z = acc[mt][0][2] + bb; o4.w = acc[mt][0][3] + bb;
                *(float4*)(of + (size_t)(b * 63 + col) * N_PTS + nrow0 + mt * 16 + kg * 4) = o4;
            }
        }
    }
}

// ---------------- MODE 2-style GEMM (contiguous packed A), packed output via LDS transpose ----------------
template<int MODE, int MT, int NT, int KD, int NTOT>
__global__ __launch_bounds__(256) void gemm_mfma_t(
    const unsigned* __restrict__ A0,
    const short* __restrict__ Bh, const short* __restrict__ Bl,
    const float* __restrict__ sv, const float* __restrict__ bvv,
    const float* __restrict__ extra, unsigned* __restrict__ op)
{
    const int t = threadIdx.x;
    const int w = t >> 6, lane = t & 63;
    const int cn = lane & 15, kg = lane >> 4;
    const int m0 = blockIdx.x * (MT * 16);
    const int n0 = blockIdx.y * (NT * 64);

    __shared__ __align__(16) short Abuf2[2 * MT * 16 * 40 > 2 * 16 * 132 * 2 ? 2 * MT * 16 * 40 : 2 * 16 * 132 * 2];
    short* A_hi = Abuf2;
    short* A_lo = Abuf2 + MT * 16 * 40;

    f32x4 acc[MT][NT];
#pragma unroll
    for (int mt = 0; mt < MT; ++mt)
#pragma unroll
        for (int nt = 0; nt < NT; ++nt) acc[mt][nt] = (f32x4){0.f, 0.f, 0.f, 0.f};

    for (int kc = 0; kc < KD / 32; ++kc) {
        {
            const int kq = (t & 7) * 4;
            const int r0 = t >> 3;
#pragma unroll
            for (int rr = 0; rr < (MT * 16) / 32; ++rr) {
                int row = r0 + rr * 32;
                int gk = kc * 32 + kq;
                uint4 v = *(const uint4*)(A0 + (size_t)(m0 + row) * KD + gk);
                short4 h, l;
                h.x = (short)(v.x >> 16); l.x = (short)v.x;
                h.y = (short)(v.y >> 16); l.y = (short)v.y;
                h.z = (short)(v.z >> 16); l.z = (short)v.z;
                h.w = (short)(v.w >> 16); l.w = (short)v.w;
                *(short4*)(A_hi + row * 40 + kq) = h;
                *(short4*)(A_lo + row * 40 + kq) = l;
            }
        }
        __syncthreads();
        bf16x8 bh[NT], bl[NT];
#pragma unroll
        for (int nt = 0; nt < NT; ++nt) {
            int col = n0 + (w * NT + nt) * 16 + cn;
            int boff = col * KD + kc * 32 + kg * 8;
            bh[nt] = *(const bf16x8*)(Bh + boff);
            bl[nt] = *(const bf16x8*)(Bl + boff);
        }
#pragma unroll
        for (int mt = 0; mt < MT; ++mt) {
            int ao = (mt * 16 + cn) * 40 + kg * 8;
            bf16x8 ah = *(const bf16x8*)(A_hi + ao);
            bf16x8 al = *(const bf16x8*)(A_lo + ao);
#pragma unroll
            for (int nt = 0; nt < NT; ++nt) {
                acc[mt][nt] = __builtin_amdgcn_mfma_f32_16x16x32_bf16(al, bh[nt], acc[mt][nt], 0, 0, 0);
                acc[mt][nt] = __builtin_amdgcn_mfma_f32_16x16x32_bf16(ah, bl[nt], acc[mt][nt], 0, 0, 0);
                acc[mt][nt] = __builtin_amdgcn_mfma_f32_16x16x32_bf16(ah, bh[nt], acc[mt][nt], 0, 0, 0);
            }
        }
        __syncthreads();
    }

    unsigned* T = (unsigned*)Abuf2;
    const int b = m0 >> 12;
#pragma unroll
    for (int mt = 0; mt < MT; ++mt) {
#pragma unroll
        for (int nt = 0; nt < NT; ++nt) {
            int col = n0 + (w * NT + nt) * 16 + cn;
            float s = sv[col], bb = bvv[col];
            float cc = (MODE == 1) ? extra[b * 512 + col] : 0.0f;
#pragma unroll
            for (int r = 0; r < 4; ++r) {
                float v = lrelu((acc[mt][nt][r] + cc) * s + bb);
                T[(kg * 4 + r) * 132 + (w * NT + nt) * 16 + cn] = packbf(v);
            }
        }
        __syncthreads();
        {
            int row = t >> 4, c0 = (t & 15) * 8;
            uint4 u0 = *(uint4*)(T + row * 132 + c0);
            uint4 u1 = *(uint4*)(T + row * 132 + c0 + 4);
            int grow = m0 + mt * 16 + row;
            *(uint4*)(op + (size_t)grow * NTOT + n0 + c0) = u0;
            *(uint4*)(op + (size_t)grow * NTOT + n0 + c0 + 4) = u1;
        }
        __syncthreads();
    }
}

// ---------------- MODE 1 GEMM (three packed x-arrays), +c7 epilogue, packed output ----------------
template<int MT, int NT, int KD, int NTOT>
__global__ __launch_bounds__(256) void gemm_mfma_c7(
    const unsigned* __restrict__ A0, const unsigned* __restrict__ A1, const unsigned* __restrict__ A2,
    const short* __restrict__ Bh, const short* __restrict__ Bl,
    const float* __restrict__ sv, const float* __restrict__ bvv,
    const float* __restrict__ extra, unsigned* __restrict__ op)
{
    const int t = threadIdx.x;
    const int w = t >> 6, lane = t & 63;
    const int cn = lane & 15, kg = lane >> 4;
    const int m0 = blockIdx.x * (MT * 16);
    const int n0 = blockIdx.y * (NT * 64);

    __shared__ __align__(16) short Abuf2[2 * MT * 16 * 40 > 2 * 16 * 132 * 2 ? 2 * MT * 16 * 40 : 2 * 16 * 132 * 2];
    short* A_hi = Abuf2;
    short* A_lo = Abuf2 + MT * 16 * 40;

    f32x4 acc[MT][NT];
#pragma unroll
    for (int mt = 0; mt < MT; ++mt)
#pragma unroll
        for (int nt = 0; nt < NT; ++nt) acc[mt][nt] = (f32x4){0.f, 0.f, 0.f, 0.f};

    for (int kc = 0; kc < KD / 32; ++kc) {
        {
            const int kq = (t & 7) * 4;
            const int r0 = t >> 3;
#pragma unroll
            for (int rr = 0; rr < (MT * 16) / 32; ++rr) {
                int row = r0 + rr * 32;
                int gk = kc * 32 + kq;
                const unsigned* srcp = (gk < 64) ? A0 : ((gk < 128) ? A1 : A2);
                uint4 v = *(const uint4*)(srcp + (size_t)(m0 + row) * 64 + (gk & 63));
                short4 h, l;
                h.x = (short)(v.x >> 16); l.x = (short)v.x;
                h.y = (short)(v.y >> 16); l.y = (short)v.y;
                h.z = (short)(v.z >> 16); l.z = (short)v.z;
                h.w = (short)(v.w >> 16); l.w = (short)v.w;
                *(short4*)(A_hi + row * 40 + kq) = h;
                *(short4*)(A_lo + row * 40 + kq) = l;
            }
        }
        __syncthreads();
        bf16x8 bh[NT], bl[NT];
#pragma unroll
        for (int nt = 0; nt < NT; ++nt) {
            int col = n0 + (w * NT + nt) * 16 + cn;
            int boff = col * KD + kc * 32 + kg * 8;
            bh[nt] = *(const bf16x8*)(Bh + boff);
            bl[nt] = *(const bf16x8*)(Bl + boff);
        }
#pragma unroll
        for (int mt = 0; mt < MT; ++mt) {
            int ao = (mt * 16 + cn) * 40 + kg * 8;
            bf16x8 ah = *(const bf16x8*)(A_hi + ao);
            bf16x8 al = *(const bf16x8*)(A_lo + ao);
#pragma unroll
            for (int nt = 0; nt < NT; ++nt) {
                acc[mt][nt] = __builtin_amdgcn_mfma_f32_16x16x32_bf16(al, bh[nt], acc[mt][nt], 0, 0, 0);
                acc[mt][nt] = __builtin_amdgcn_mfma_f32_16x16x32_bf16(ah, bl[nt], acc[mt][nt], 0, 0, 0);
                acc[mt][nt] = __builtin_amdgcn_mfma_f32_16x16x32_bf16(ah, bh[nt], acc[mt][nt], 0, 0, 0);
            }
        }
        __syncthreads();
    }

    unsigned* T = (unsigned*)Abuf2;
    const int b = m0 >> 12;
#pragma unroll
    for (int mt = 0; mt < MT; ++mt) {
#pragma unroll
        for (int nt = 0; nt < NT; ++nt) {
            int col = n0 + (w * NT + nt) * 16 + cn;
            float s = sv[col], bb = bvv[col];
            float cc = extra[b * 512 + col];
#pragma unroll
            for (int r = 0; r < 4; ++r) {
                float v = lrelu((acc[mt][nt][r] + cc) * s + bb);
                T[(kg * 4 + r) * 132 + (w * NT + nt) * 16 + cn] = packbf(v);
            }
        }
        __syncthreads();
        {
            int row = t >> 4, c0 = (t & 15) * 8;
            uint4 u0 = *(uint4*)(T + row * 132 + c0);
            uint4 u1 = *(uint4*)(T + row * 132 + c0 + 4);
            int grow = m0 + mt * 16 + row;
            *(uint4*)(op + (size_t)grow * NTOT + n0 + c0) = u0;
            *(uint4*)(op + (size_t)grow * NTOT + n0 + c0 + 4) = u1;
        }
        __syncthreads();
    }
}

__global__ __launch_bounds__(256) void greduce_kernel(const float* __restrict__ gpart, float* __restrict__ g)
{
    int tid = blockIdx.x * 256 + threadIdx.x;   // 4096
    int b = tid >> 10, o = tid & 1023;
    float m = -1e30f;
    for (int q = 0; q < 32; ++q) m = fmaxf(m, gpart[(b * 32 + q) * 1024 + o]);
    g[tid] = m;
}

__global__ __launch_bounds__(256) void c7_kernel(const float* __restrict__ g, const float* __restrict__ W7,
                                                 float* __restrict__ c7)
{
    int tid = blockIdx.x * 256 + threadIdx.x;   // 2048
    int b = tid >> 9, o = tid & 511;
    const float* gb = g + b * 1024;
    const float* wr = W7 + o * 1216;
    float s = 0.0f;
    for (int i = 0; i < 1024; i += 4) {
        float4 wv4 = *reinterpret_cast<const float4*>(&wr[i]);
        float4 gv4 = *reinterpret_cast<const float4*>(&gb[i]);
        s += wv4.x * gv4.x + wv4.y * gv4.y + wv4.z * gv4.z + wv4.w * gv4.w;
    }
    c7[tid] = s;
}

extern "C" void kernel_launch(void* const* d_in, const int* in_sizes, int n_in,
                              void* d_out, int out_size, void* d_ws, size_t ws_size,
                              hipStream_t stream)
{
    const float* x  = (const float*)d_in[0];
    const float* W1 = (const float*)d_in[1];
    const float* s1 = (const float*)d_in[2];
    const float* b1 = (const float*)d_in[3];
    const float* W2 = (const float*)d_in[4];
    const float* s2 = (const float*)d_in[5];
    const float* b2 = (const float*)d_in[6];
    const float* W3 = (const float*)d_in[7];
    const float* s3 = (const float*)d_in[8];
    const float* b3 = (const float*)d_in[9];
    const float* W4 = (const float*)d_in[10];
    const float* s4 = (const float*)d_in[11];
    const float* b4 = (const float*)d_in[12];
    const float* W5 = (const float*)d_in[13];
    const float* s5 = (const float*)d_in[14];
    const float* b5 = (const float*)d_in[15];
    const float* W6 = (const float*)d_in[16];
    const float* s6 = (const float*)d_in[17];
    const float* b6 = (const float*)d_in[18];
    const float* W7 = (const float*)d_in[19];
    const float* s7 = (const float*)d_in[20];
    const float* b7 = (const float*)d_in[21];
    const float* W8 = (const float*)d_in[22];
    const float* s8 = (const float*)d_in[23];
    const float* b8 = (const float*)d_in[24];
    const float* W9 = (const float*)d_in[25];
    const float* b9 = (const float*)d_in[26];

    char* ws = (char*)d_ws;
    int*      idx   = (int*)(ws);                      // 2.62 MB
    float*    x1    = (float*)(ws + 2621440);
    float*    x2    = (float*)(ws + 6815744);
    float*    x3    = (float*)(ws + 11010048);
    unsigned* x1p   = (unsigned*)(ws + 15204352);
    unsigned* x2p   = (unsigned*)(ws + 19398656);
    unsigned* x3p   = (unsigned*)(ws + 23592960);
    float*    gpart = (float*)(ws + 27787264);         // 128*1024
    float*    g     = (float*)(ws + 28311552);
    float*    c7    = (float*)(ws + 28327936);
    short*    w3h   = (short*)(ws + 28336128);
    short*    w3l   = w3h + 4096;
    short*    w4h   = w3h + 8192;
    short*    w4l   = w3h + 12288;
    short*    w5h   = w3h + 16384;
    short*    w5l   = w3h + 20480;
    float*    wdt3  = (float*)(ws + 28385280);
    float*    wdt5  = (float*)(ws + 28401664);
    short*    w6h   = (short*)(ws + 28418048);         // 196608 shorts
    short*    w6l   = (short*)(ws + 28811264);
    short*    w7h   = (short*)(ws + 29204480);         // 98304
    short*    w7l   = (short*)(ws + 29401088);
    short*    w8h   = (short*)(ws + 29597696);         // 131072
    short*    w8l   = (short*)(ws + 29859840);
    short*    w9h   = (short*)(ws + 30121984);         // 16384
    short*    w9l   = (short*)(ws + 30154752);
    unsigned* h7p   = (unsigned*)(ws + 30408704);      // 33.55 MB -> ends 63963136
    unsigned* h8p   = (unsigned*)(ws);                 // 16.78 MB, aliases dead early buffers
    float*    outp  = (float*)d_out;

    knn_kernel<<<BATCH * N_PTS, 256, 0, stream>>>(x, idx);
    prep_kernel<<<16, 256, 0, stream>>>(W3, W4, W5, w3h, w3l, w4h, w4l, w5h, w5l, wdt3, wdt5);
    prep2_kernel<<<1728, 256, 0, stream>>>(W6, W7, W8, W9, w6h, w6l, w7h, w7l, w8h, w8l, w9h, w9l);
    layer1_kernel<<<BATCH * N_PTS, 256, 0, stream>>>(x, idx, W1, s1, b1, W2, s2, b2, x1, x1p);
    edge_mfma_kernel<1><<<BATCH * N_PTS / 2, 256, 0, stream>>>(x1, idx, w3h, w3l, wdt3, s3, b3, w4h, w4l, s4, b4, x2, x2p);
    edge_mfma_kernel<0><<<BATCH * N_PTS / 2, 256, 0, stream>>>(x2, idx, w5h, w5l, wdt5, s5, b5, nullptr, nullptr, nullptr, nullptr, x3, x3p);
    gemm_mfma<0, 8, 2, 192, 1024><<<dim3(128, 8), 256, 0, stream>>>(x1p, x2p, x3p, w6h, w6l, s6, b6, nullptr, gpart);
    greduce_kernel<<<16, 256, 0, stream>>>(gpart, g);
    c7_kernel<<<8, 256, 0, stream>>>(g, W7, c7);
    gemm_mfma_c7<8, 2, 192, 512><<<dim3(128, 4), 256, 0, stream>>>(x1p, x2p, x3p, w7h, w7l, s7, b7, c7, h7p);
    gemm_mfma_t<2, 4, 2, 512, 256><<<dim3(256, 2), 256, 0, stream>>>(h7p, w8h, w8l, s8, b8, nullptr, h8p);
    gemm_mfma<3, 4, 1, 256, 64><<<dim3(256, 1), 256, 0, stream>>>(h8p, nullptr, nullptr, w9h, w9l, nullptr, b9, nullptr, outp);
}

// Round 5
// 514.800 us; speedup vs baseline: 2.1152x; 1.1352x over previous
//
#include <hip/hip_runtime.h>

#define N_PTS 4096
#define KNBR 40
#define BATCH 4

typedef __attribute__((ext_vector_type(8))) short bf16x8;
typedef __attribute__((ext_vector_type(4))) float f32x4;

__device__ __forceinline__ float lrelu(float v) { return v > 0.0f ? v : 0.2f * v; }

__device__ __forceinline__ short bf16_rn(float f) {
    unsigned u = __float_as_uint(f);
    unsigned r = (u + 0x7FFFu + ((u >> 16) & 1u)) >> 16;
    return (short)r;
}
__device__ __forceinline__ float bf16f(short h) {
    return __uint_as_float(((unsigned)(unsigned short)h) << 16);
}
__device__ __forceinline__ unsigned packbf(float v) {
    short h = bf16_rn(v);
    float r = v - bf16f(h);
    short l = bf16_rn(r);
    return (((unsigned)(unsigned short)h) << 16) | (unsigned)(unsigned short)l;
}

// ---------------- KNN: exact top-40 via two-level radix select on ordered-uint keys ----------------
__global__ __launch_bounds__(256) void knn_kernel(const float* __restrict__ x, int* __restrict__ idxo)
{
    const int t = threadIdx.x;
    const int pt = blockIdx.x;
    const int b = pt >> 12, n = pt & 4095;
    const float* xb = x + b * 3 * N_PTS;
    const int lane = t & 63, wv = t >> 6;

    __shared__ unsigned hist[4096];
    __shared__ unsigned wtot[4];
    __shared__ int sh[8];          // 0:B1 1:nAbove1 2:needRef 3:emitPos 4:B2 5:nAbove2 6:candCnt 7:R(target)
    __shared__ unsigned cov[128];
    __shared__ int cidx[128];

    const float c0 = xb[n], c1 = xb[N_PTS + n], c2 = xb[2 * N_PTS + n];
    const float cc = c0 * c0 + c1 * c1 + c2 * c2;

    unsigned ov[16];
#pragma unroll
    for (int j = 0; j < 16; ++j) {
        int m = t + j * 256;
        float a0 = xb[m], a1 = xb[N_PTS + m], a2 = xb[2 * N_PTS + m];
        float d = 2.0f * (c0 * a0 + c1 * a1 + c2 * a2) - cc - (a0 * a0 + a1 * a1 + a2 * a2);
        unsigned u = __float_as_uint(d);
        ov[j] = (u & 0x80000000u) ? ~u : (u | 0x80000000u);
    }

#pragma unroll
    for (int j = 0; j < 16; ++j) hist[t + j * 256] = 0;
    if (t < 8) sh[t] = 0;
    __syncthreads();
#pragma unroll
    for (int j = 0; j < 16; ++j) atomicAdd(&hist[ov[j] >> 20], 1u);
    __syncthreads();

    // ---- level 1 select: chunk sums + suffix scan (chunk t = bins [16t,16t+16)) ----
    unsigned cs = 0;
#pragma unroll
    for (int q = 0; q < 16; ++q) cs += hist[t * 16 + q];
    unsigned val = cs;
#pragma unroll
    for (int off = 1; off < 64; off <<= 1) {
        unsigned o = __shfl_down(val, off, 64);
        if (lane + off < 64) val += o;
    }
    if (lane == 0) wtot[wv] = val;
    __syncthreads();
    unsigned above_w = 0;
    for (int q = wv + 1; q < 4; ++q) above_w += wtot[q];
    unsigned Sincl = val + above_w;
    unsigned excl = Sincl - cs;
    if (excl < KNBR && Sincl >= KNBR) { sh[0] = t; sh[1] = (int)excl; }
    __syncthreads();
    if (t == 0) {
        int tstar = sh[0];
        unsigned run = (unsigned)sh[1];
        int B1 = -1; unsigned nab = 0;
        for (int q = 15; q >= 0; --q) {
            int bb = tstar * 16 + q;
            unsigned h = hist[bb];
            if (run + h >= KNBR) { B1 = bb; nab = run; break; }
            run += h;
        }
        sh[0] = B1; sh[1] = (int)nab;
        int R1 = KNBR - (int)nab;
        sh[7] = R1;
        sh[2] = ((int)hist[B1] > R1) ? 1 : 0;   // need refinement?
    }
    __syncthreads();
    const unsigned B1 = (unsigned)sh[0];
    const int needRef = sh[2];
    const int R1 = sh[7];

    // emit strictly-above-bin values
#pragma unroll
    for (int j = 0; j < 16; ++j) {
        unsigned bb = ov[j] >> 20;
        if (bb > B1) { int p = atomicAdd(&sh[3], 1); idxo[pt * KNBR + p] = t + j * 256; }
        else if (bb == B1 && !needRef) { int p = atomicAdd(&sh[3], 1); idxo[pt * KNBR + p] = t + j * 256; }
    }
    if (!needRef) return;

    // ---- level 2: refine within bin B1 on bits [19:8] ----
    __syncthreads();
#pragma unroll
    for (int j = 0; j < 16; ++j) hist[t + j * 256] = 0;
    __syncthreads();
#pragma unroll
    for (int j = 0; j < 16; ++j)
        if ((ov[j] >> 20) == B1) atomicAdd(&hist[(ov[j] >> 8) & 0xFFFu], 1u);
    __syncthreads();
    cs = 0;
#pragma unroll
    for (int q = 0; q < 16; ++q) cs += hist[t * 16 + q];
    val = cs;
#pragma unroll
    for (int off = 1; off < 64; off <<= 1) {
        unsigned o = __shfl_down(val, off, 64);
        if (lane + off < 64) val += o;
    }
    if (lane == 0) wtot[wv] = val;
    __syncthreads();
    above_w = 0;
    for (int q = wv + 1; q < 4; ++q) above_w += wtot[q];
    Sincl = val + above_w;
    excl = Sincl - cs;
    if ((int)excl < R1 && (int)Sincl >= R1) { sh[4] = t; sh[5] = (int)excl; }
    __syncthreads();
    if (t == 0) {
        int tstar = sh[4];
        unsigned run = (unsigned)sh[5];
        int B2 = -1; unsigned nab = 0;
        for (int q = 15; q >= 0; --q) {
            int bb = tstar * 16 + q;
            unsigned h = hist[bb];
            if ((int)(run + h) >= R1) { B2 = bb; nab = run; break; }
            run += h;
        }
        sh[4] = B2; sh[5] = (int)nab;
        sh[2] = ((int)hist[B2] > (R1 - (int)nab)) ? 1 : 0;  // exact fit?
        sh[6] = 0;
    }
    __syncthreads();
    const unsigned B2 = (unsigned)sh[4];
    const int R2 = R1 - sh[5];
    const int needSer = sh[2];
#pragma unroll
    for (int j = 0; j < 16; ++j) {
        if ((ov[j] >> 20) == B1) {
            unsigned b2 = (ov[j] >> 8) & 0xFFFu;
            if (b2 > B2) { int p = atomicAdd(&sh[3], 1); idxo[pt * KNBR + p] = t + j * 256; }
            else if (b2 == B2) {
                if (!needSer) { int p = atomicAdd(&sh[3], 1); idxo[pt * KNBR + p] = t + j * 256; }
                else { int q = atomicAdd(&sh[6], 1); if (q < 128) { cov[q] = ov[j]; cidx[q] = t + j * 256; } }
            }
        }
    }
    if (!needSer) return;
    __syncthreads();
    if (t == 0) {
        int tc = sh[6] < 128 ? sh[6] : 128;
        int pos = sh[3];
        for (int r = 0; r < R2; ++r) {
            unsigned bestv = 0; int besti = 0x7FFFFFFF; int bestq = -1;
            for (int q = 0; q < tc; ++q) {
                if (cidx[q] < 0) continue;
                if (bestq < 0 || cov[q] > bestv || (cov[q] == bestv && cidx[q] < besti)) {
                    bestv = cov[q]; besti = cidx[q]; bestq = q;
                }
            }
            idxo[pt * KNBR + pos + r] = besti;
            cidx[bestq] = -1;
        }
    }
}

// ---------------- Layer 1 via MFMA: conv1(6->64 VALU) + conv2(64->64 MFMA) + max, 2 pts/block ----------------
__global__ __launch_bounds__(256) void layer1_mfma_kernel(const float* __restrict__ x, const int* __restrict__ idx,
    const float* __restrict__ W1, const float* __restrict__ s1, const float* __restrict__ b1,
    const short* __restrict__ w2h, const short* __restrict__ w2l,
    const float* __restrict__ s2, const float* __restrict__ b2,
    float* __restrict__ x1out, unsigned* __restrict__ x1p)
{
    const int t = threadIdx.x;
    const int pt0 = blockIdx.x * 2;
    const int b = pt0 >> 12;
    const float* xb = x + b * 3 * N_PTS;
    const int lane = t & 63, w = t >> 6;
    const int cn = lane & 15, kg = lane >> 4;

    __shared__ int idxs[80];
    __shared__ float w1t[384];          // [6][64] transposed W1
    __shared__ float ctrv[2][64];
    __shared__ float nbrc[80][4];
    __shared__ float Abuf[5808];
    short* A_hi = (short*)Abuf;
    short* A_lo = A_hi + 80 * 72;
    float* red = Abuf;

    if (t < 80) idxs[t] = idx[pt0 * KNBR + t];
    if (t < 64) {
#pragma unroll
        for (int j = 0; j < 6; ++j) w1t[j * 64 + t] = W1[t * 6 + j];
    }
    __syncthreads();
    if (t < 240) { int k = t / 3, j = t % 3; nbrc[k][j] = xb[j * N_PTS + idxs[k]]; }
    if (t < 128) {
        int p = t >> 6, o = t & 63;
        int n = (pt0 + p) & 4095;
        float cx = xb[n], cy = xb[N_PTS + n], cz = xb[2 * N_PTS + n];
        ctrv[p][o] = (w1t[192 + o] - w1t[o]) * cx + (w1t[256 + o] - w1t[64 + o]) * cy
                   + (w1t[320 + o] - w1t[128 + o]) * cz;
    }
    // B fragments for conv2 (held in registers)
    bf16x8 bh[2], bl[2];
#pragma unroll
    for (int kc = 0; kc < 2; ++kc) {
        int off = (w * 16 + cn) * 64 + kc * 32 + kg * 8;
        bh[kc] = *(const bf16x8*)(w2h + off);
        bl[kc] = *(const bf16x8*)(w2l + off);
    }
    __syncthreads();
    // conv1 (fp32) + scale/bias/lrelu -> split-bf16 A-operand layout
    {
        const int o = t & 63;
        const float w0 = w1t[o], w1v = w1t[64 + o], w2v = w1t[128 + o];
        const float sv = s1[o], bv = b1[o];
        const float cv0 = ctrv[0][o], cv1 = ctrv[1][o];
#pragma unroll
        for (int r = 0; r < 20; ++r) {
            int k = (t >> 6) + r * 4;
            float v = w0 * nbrc[k][0] + w1v * nbrc[k][1] + w2v * nbrc[k][2] + (k >= KNBR ? cv1 : cv0);
            v = lrelu(v * sv + bv);
            short h = bf16_rn(v);
            A_hi[k * 72 + o] = h;
            A_lo[k * 72 + o] = bf16_rn(v - bf16f(h));
        }
    }
    __syncthreads();
    // conv2 via split-bf16 MFMA: 5 m-tiles, K=64
    f32x4 acc[5];
#pragma unroll
    for (int mt = 0; mt < 5; ++mt) {
        f32x4 a = {0.f, 0.f, 0.f, 0.f};
#pragma unroll
        for (int kc = 0; kc < 2; ++kc) {
            int ao = (mt * 16 + cn) * 72 + kc * 32 + kg * 8;
            bf16x8 ah = *(const bf16x8*)(A_hi + ao);
            bf16x8 al = *(const bf16x8*)(A_lo + ao);
            a = __builtin_amdgcn_mfma_f32_16x16x32_bf16(al, bh[kc], a, 0, 0, 0);
            a = __builtin_amdgcn_mfma_f32_16x16x32_bf16(ah, bl[kc], a, 0, 0, 0);
            a = __builtin_amdgcn_mfma_f32_16x16x32_bf16(ah, bh[kc], a, 0, 0, 0);
        }
        acc[mt] = a;
    }
    const int o1 = w * 16 + cn;
    const float sB = s2[o1], bB = b2[o1];
    __syncthreads();
#pragma unroll
    for (int mt = 0; mt < 5; ++mt)
#pragma unroll
        for (int reg = 0; reg < 4; ++reg) {
            int row = mt * 16 + kg * 4 + reg;
            red[row * 68 + o1] = lrelu(acc[mt][reg] * sB + bB);
        }
    __syncthreads();
    if (t < 128) {
        int p = t >> 6, o = t & 63;
        float m = -1e30f;
#pragma unroll 8
        for (int k = 0; k < KNBR; ++k) m = fmaxf(m, red[(p * KNBR + k) * 68 + o]);
        x1out[(pt0 + p) * 64 + o] = m;
        x1p[(pt0 + p) * 64 + o] = packbf(m);
    }
}

// ---------------- prep: edge-conv + W2 weights -> bf16 hi/lo + ctr-weight transpose ----------------
__global__ __launch_bounds__(256) void prep_kernel(const float* __restrict__ W2, const float* __restrict__ W3,
    const float* __restrict__ W4, const float* __restrict__ W5,
    short* __restrict__ w2h, short* __restrict__ w2l,
    short* __restrict__ w3h, short* __restrict__ w3l,
    short* __restrict__ w4h, short* __restrict__ w4l,
    short* __restrict__ w5h, short* __restrict__ w5l,
    float* __restrict__ wdt3, float* __restrict__ wdt5)
{
    int e = blockIdx.x * 256 + threadIdx.x;   // 4096
    int o = e >> 6, i = e & 63;
    float a = W3[o * 128 + i];
    short h = bf16_rn(a);
    w3h[e] = h; w3l[e] = bf16_rn(a - bf16f(h));
    wdt3[i * 64 + o] = W3[o * 128 + 64 + i] - a;
    float c = W4[o * 64 + i];
    h = bf16_rn(c);
    w4h[e] = h; w4l[e] = bf16_rn(c - bf16f(h));
    float d = W5[o * 128 + i];
    h = bf16_rn(d);
    w5h[e] = h; w5l[e] = bf16_rn(d - bf16f(h));
    wdt5[i * 64 + o] = W5[o * 128 + 64 + i] - d;
    float e2 = W2[o * 64 + i];
    h = bf16_rn(e2);
    w2h[e] = h; w2l[e] = bf16_rn(e2 - bf16f(h));
}

// ---------------- prep2: W6/W7(slice)/W8/W9 -> split bf16 hi/lo ----------------
__global__ __launch_bounds__(256) void prep2_kernel(const float* __restrict__ W6, const float* __restrict__ W7,
    const float* __restrict__ W8, const float* __restrict__ W9,
    short* __restrict__ w6h, short* __restrict__ w6l,
    short* __restrict__ w7h, short* __restrict__ w7l,
    short* __restrict__ w8h, short* __restrict__ w8l,
    short* __restrict__ w9h, short* __restrict__ w9l)
{
    int e = blockIdx.x * 256 + threadIdx.x;
    float v; short* dh; short* dl; int di;
    if (e < 196608) {                       // W6: 1024x192
        v = W6[e]; dh = w6h; dl = w6l; di = e;
    } else if (e < 294912) {                // W7 cols 1024..1215: 512x192
        int ee = e - 196608;
        int o = ee / 192, k = ee - o * 192;
        v = W7[o * 1216 + 1024 + k]; dh = w7h; dl = w7l; di = ee;
    } else if (e < 425984) {                // W8: 256x512
        int ee = e - 294912;
        v = W8[ee]; dh = w8h; dl = w8l; di = ee;
    } else if (e < 442368) {                // W9: 64x256 (row 63 zero-pad)
        int ee = e - 425984;
        int o = ee >> 8, k = ee & 255;
        v = (o < 63) ? W9[o * 256 + k] : 0.0f;
        dh = w9h; dl = w9l; di = ee;
    } else return;
    short h = bf16_rn(v);
    dh[di] = h; dl[di] = bf16_rn(v - bf16f(h));
}

// ---------------- Edge layers via MFMA (split-bf16), 2 points/block, M=80 ----------------
template<int HAS2>
__global__ __launch_bounds__(256) void edge_mfma_kernel(const float* __restrict__ src, const int* __restrict__ idx,
    const short* __restrict__ wah, const short* __restrict__ wal, const float* __restrict__ wdt,
    const float* __restrict__ sa, const float* __restrict__ ba,
    const short* __restrict__ wbh, const short* __restrict__ wbl,
    const float* __restrict__ sb, const float* __restrict__ bb,
    float* __restrict__ xout, unsigned* __restrict__ xpout)
{
    const int t = threadIdx.x;
    const int pt0 = blockIdx.x * 2;
    const int b = pt0 >> 12;
    const int lane = t & 63, w = t >> 6;
    const int cn = lane & 15, kg = lane >> 4;

    __shared__ int idxs[80];
    __shared__ float ctr1[2][64];
    __shared__ float ctrv[2][64];
    __shared__ float Abuf[5808];
    short* A_hi = (short*)Abuf;
    short* A_lo = A_hi + 80 * 72;
    float* red = Abuf;

    if (t < 80) idxs[t] = idx[pt0 * KNBR + t];
    if (t >= 128) { int p = (t >> 6) & 1; int i = t & 63; ctr1[p][i] = src[(pt0 + p) * 64 + i]; }
    __syncthreads();

    bf16x8 bh[2], bl[2];
#pragma unroll
    for (int kc = 0; kc < 2; ++kc) {
        int off = (w * 16 + cn) * 64 + kc * 32 + kg * 8;
        bh[kc] = *(const bf16x8*)(wah + off);
        bl[kc] = *(const bf16x8*)(wal + off);
    }

    {
        const int r0 = t >> 4, c4 = (t & 15) * 4;
#pragma unroll
        for (int r = 0; r < 5; ++r) {
            int row = r * 16 + r0;
            const float4 v = *(const float4*)(src + (size_t)(b * N_PTS + idxs[row]) * 64 + c4);
            short4 h, l;
            h.x = bf16_rn(v.x); l.x = bf16_rn(v.x - bf16f(h.x));
            h.y = bf16_rn(v.y); l.y = bf16_rn(v.y - bf16f(h.y));
            h.z = bf16_rn(v.z); l.z = bf16_rn(v.z - bf16f(h.z));
            h.w = bf16_rn(v.w); l.w = bf16_rn(v.w - bf16f(h.w));
            *(short4*)(A_hi + row * 72 + c4) = h;
            *(short4*)(A_lo + row * 72 + c4) = l;
        }
    }
    if (t < 128) {
        int p = t >> 6, o = t & 63;
        float s = 0.0f;
#pragma unroll 8
        for (int i = 0; i < 64; ++i) s = fmaf(wdt[i * 64 + o], ctr1[p][i], s);
        ctrv[p][o] = s;
    }
    __syncthreads();

    f32x4 acc[5];
#pragma unroll
    for (int mt = 0; mt < 5; ++mt) {
        f32x4 a = {0.f, 0.f, 0.f, 0.f};
#pragma unroll
        for (int kc = 0; kc < 2; ++kc) {
            int ao = (mt * 16 + cn) * 72 + kc * 32 + kg * 8;
            bf16x8 ah = *(const bf16x8*)(A_hi + ao);
            bf16x8 al = *(const bf16x8*)(A_lo + ao);
            a = __builtin_amdgcn_mfma_f32_16x16x32_bf16(al, bh[kc], a, 0, 0, 0);
            a = __builtin_amdgcn_mfma_f32_16x16x32_bf16(ah, bl[kc], a, 0, 0, 0);
            a = __builtin_amdgcn_mfma_f32_16x16x32_bf16(ah, bh[kc], a, 0, 0, 0);
        }
        acc[mt] = a;
    }

    const int o1 = w * 16 + cn;
    const float sA = sa[o1], bA = ba[o1];
    __syncthreads();

    if (HAS2) {
#pragma unroll
        for (int mt = 0; mt < 5; ++mt) {
#pragma unroll
            for (int reg = 0; reg < 4; ++reg) {
                int row = mt * 16 + kg * 4 + reg;
                int p = row >= KNBR;
                float v = lrelu((acc[mt][reg] + ctrv[p][o1]) * sA + bA);
                short h = bf16_rn(v);
                A_hi[row * 72 + o1] = h;
                A_lo[row * 72 + o1] = bf16_rn(v - bf16f(h));
            }
        }
        __syncthreads();
#pragma unroll
        for (int kc = 0; kc < 2; ++kc) {
            int off = (w * 16 + cn) * 64 + kc * 32 + kg * 8;
            bh[kc] = *(const bf16x8*)(wbh + off);
            bl[kc] = *(const bf16x8*)(wbl + off);
        }
#pragma unroll
        for (int mt = 0; mt < 5; ++mt) {
            f32x4 a = {0.f, 0.f, 0.f, 0.f};
#pragma unroll
            for (int kc = 0; kc < 2; ++kc) {
                int ao = (mt * 16 + cn) * 72 + kc * 32 + kg * 8;
                bf16x8 ah = *(const bf16x8*)(A_hi + ao);
                bf16x8 al = *(const bf16x8*)(A_lo + ao);
                a = __builtin_amdgcn_mfma_f32_16x16x32_bf16(al, bh[kc], a, 0, 0, 0);
                a = __builtin_amdgcn_mfma_f32_16x16x32_bf16(ah, bl[kc], a, 0, 0, 0);
                a = __builtin_amdgcn_mfma_f32_16x16x32_bf16(ah, bh[kc], a, 0, 0, 0);
            }
            acc[mt] = a;
        }
        const float sB = sb[o1], bB = bb[o1];
        __syncthreads();
#pragma unroll
        for (int mt = 0; mt < 5; ++mt) {
#pragma unroll
            for (int reg = 0; reg < 4; ++reg) {
                int row = mt * 16 + kg * 4 + reg;
                red[row * 68 + o1] = lrelu(acc[mt][reg] * sB + bB);
            }
        }
    } else {
#pragma unroll
        for (int mt = 0; mt < 5; ++mt) {
#pragma unroll
            for (int reg = 0; reg < 4; ++reg) {
                int row = mt * 16 + kg * 4 + reg;
                int p = row >= KNBR;
                red[row * 68 + o1] = lrelu((acc[mt][reg] + ctrv[p][o1]) * sA + bA);
            }
        }
    }
    __syncthreads();
    if (t < 128) {
        int p = t >> 6, o = t & 63;
        float m = -1e30f;
#pragma unroll 8
        for (int k = 0; k < KNBR; ++k) m = fmaxf(m, red[(p * KNBR + k) * 68 + o]);
        xout[(pt0 + p) * 64 + o] = m;
        xpout[(pt0 + p) * 64 + o] = packbf(m);
    }
}

// ---------------- Split-bf16 MFMA GEMM, fused epilogues ----------------
// MODE 0: conv6 (A=x123p K=192, lrelu, per-block col-max -> gpart)
// MODE 3: conv9 (A=h8p K=256, +b9, transposed fp32 store, col<63)
template<int MODE, int MT, int NT, int KD, int NTOT>
__global__ __launch_bounds__(256) void gemm_mfma(
    const unsigned* __restrict__ A0, const unsigned* __restrict__ A1, const unsigned* __restrict__ A2,
    const short* __restrict__ Bh, const short* __restrict__ Bl,
    const float* __restrict__ sv, const float* __restrict__ bvv,
    const float* __restrict__ extra, void* __restrict__ outp)
{
    const int t = threadIdx.x;
    const int w = t >> 6, lane = t & 63;
    const int cn = lane & 15, kg = lane >> 4;
    const int m0 = blockIdx.x * (MT * 16);
    const int n0 = blockIdx.y * (NT * 64);

    __shared__ __align__(16) short Abuf2[2 * MT * 16 * 40];
    short* A_hi = Abuf2;
    short* A_lo = Abuf2 + MT * 16 * 40;

    f32x4 acc[MT][NT];
#pragma unroll
    for (int mt = 0; mt < MT; ++mt)
#pragma unroll
        for (int nt = 0; nt < NT; ++nt) acc[mt][nt] = (f32x4){0.f, 0.f, 0.f, 0.f};

    for (int kc = 0; kc < KD / 32; ++kc) {
        // stage A k-chunk (32) into LDS hi/lo planes
        {
            const int kq = (t & 7) * 4;
            const int r0 = t >> 3;
#pragma unroll
            for (int rr = 0; rr < (MT * 16) / 32; ++rr) {
                int row = r0 + rr * 32;
                int gk = kc * 32 + kq;
                uint4 v;
                if (MODE == 0) {
                    const unsigned* srcp = (gk < 64) ? A0 : ((gk < 128) ? A1 : A2);
                    v = *(const uint4*)(srcp + (size_t)(m0 + row) * 64 + (gk & 63));
                } else {
                    v = *(const uint4*)(A0 + (size_t)(m0 + row) * KD + gk);
                }
                short4 h, l;
                h.x = (short)(v.x >> 16); l.x = (short)v.x;
                h.y = (short)(v.y >> 16); l.y = (short)v.y;
                h.z = (short)(v.z >> 16); l.z = (short)v.z;
                h.w = (short)(v.w >> 16); l.w = (short)v.w;
                *(short4*)(A_hi + row * 40 + kq) = h;
                *(short4*)(A_lo + row * 40 + kq) = l;
            }
        }
        __syncthreads();
        bf16x8 bh[NT], bl[NT];
#pragma unroll
        for (int nt = 0; nt < NT; ++nt) {
            int col = n0 + (w * NT + nt) * 16 + cn;
            int boff = col * KD + kc * 32 + kg * 8;
            bh[nt] = *(const bf16x8*)(Bh + boff);
            bl[nt] = *(const bf16x8*)(Bl + boff);
        }
#pragma unroll
        for (int mt = 0; mt < MT; ++mt) {
            int ao = (mt * 16 + cn) * 40 + kg * 8;
            bf16x8 ah = *(const bf16x8*)(A_hi + ao);
            bf16x8 al = *(const bf16x8*)(A_lo + ao);
#pragma unroll
            for (int nt = 0; nt < NT; ++nt) {
                acc[mt][nt] = __builtin_amdgcn_mfma_f32_16x16x32_bf16(al, bh[nt], acc[mt][nt], 0, 0, 0);
                acc[mt][nt] = __builtin_amdgcn_mfma_f32_16x16x32_bf16(ah, bl[nt], acc[mt][nt], 0, 0, 0);
                acc[mt][nt] = __builtin_amdgcn_mfma_f32_16x16x32_bf16(ah, bh[nt], acc[mt][nt], 0, 0, 0);
            }
        }
        __syncthreads();
    }

    if (MODE == 0) {
        float* gp = (float*)outp;
#pragma unroll
        for (int nt = 0; nt < NT; ++nt) {
            int col = n0 + (w * NT + nt) * 16 + cn;
            float s = sv[col], bb = bvv[col];
            float mx = -1e30f;
#pragma unroll
            for (int mt = 0; mt < MT; ++mt)
#pragma unroll
                for (int r = 0; r < 4; ++r) mx = fmaxf(mx, lrelu(acc[mt][nt][r] * s + bb));
            mx = fmaxf(mx, __shfl_xor(mx, 16, 64));
            mx = fmaxf(mx, __shfl_xor(mx, 32, 64));
            if (kg == 0) gp[blockIdx.x * NTOT + col] = mx;
        }
    } else {
        float* of = (float*)outp;
        const int b = m0 >> 12;
        const int nrow0 = m0 & 4095;
        int col = w * 16 + cn;
        if (col < 63) {
            float bb = bvv[col];
#pragma unroll
            for (int mt = 0; mt < MT; ++mt) {
                float4 o4;
                o4.x = acc[mt][0][0] + bb; o4.y = acc[mt][0][1] + bb;
                o4.z = acc[mt][0][2] + bb; o4.w = acc[mt][0][3] + bb;
                *(float4*)(of + (size_t)(b * 63 + col) * N_PTS + nrow0 + mt * 16 + kg * 4) = o4;
            }
        }
    }
}

// ---------------- MODE 2-style GEMM (contiguous packed A), packed output via LDS transpose ----------------
template<int MODE, int MT, int NT, int KD, int NTOT>
__global__ __launch_bounds__(256) void gemm_mfma_t(
    const unsigned* __restrict__ A0,
    const short* __restrict__ Bh, const short* __restrict__ Bl,
    const float* __restrict__ sv, const float* __restrict__ bvv,
    const float* __restrict__ extra, unsigned* __restrict__ op)
{
    const int t = threadIdx.x;
    const int w = t >> 6, lane = t & 63;
    const int cn = lane & 15, kg = lane >> 4;
    const int m0 = blockIdx.x * (MT * 16);
    const int n0 = blockIdx.y * (NT * 64);

    __shared__ __align__(16) short Abuf2[2 * MT * 16 * 40 > 2 * 16 * 132 * 2 ? 2 * MT * 16 * 40 : 2 * 16 * 132 * 2];
    short* A_hi = Abuf2;
    short* A_lo = Abuf2 + MT * 16 * 40;

    f32x4 acc[MT][NT];
#pragma unroll
    for (int mt = 0; mt < MT; ++mt)
#pragma unroll
        for (int nt = 0; nt < NT; ++nt) acc[mt][nt] = (f32x4){0.f, 0.f, 0.f, 0.f};

    for (int kc = 0; kc < KD / 32; ++kc) {
        {
            const int kq = (t & 7) * 4;
            const int r0 = t >> 3;
#pragma unroll
            for (int rr = 0; rr < (MT * 16) / 32; ++rr) {
                int row = r0 + rr * 32;
                int gk = kc * 32 + kq;
                uint4 v = *(const uint4*)(A0 + (size_t)(m0 + row) * KD + gk);
                short4 h, l;
                h.x = (short)(v.x >> 16); l.x = (short)v.x;
                h.y = (short)(v.y >> 16); l.y = (short)v.y;
                h.z = (short)(v.z >> 16); l.z = (short)v.z;
                h.w = (short)(v.w >> 16); l.w = (short)v.w;
                *(short4*)(A_hi + row * 40 + kq) = h;
                *(short4*)(A_lo + row * 40 + kq) = l;
            }
        }
        __syncthreads();
        bf16x8 bh[NT], bl[NT];
#pragma unroll
        for (int nt = 0; nt < NT; ++nt) {
            int col = n0 + (w * NT + nt) * 16 + cn;
            int boff = col * KD + kc * 32 + kg * 8;
            bh[nt] = *(const bf16x8*)(Bh + boff);
            bl[nt] = *(const bf16x8*)(Bl + boff);
        }
#pragma unroll
        for (int mt = 0; mt < MT; ++mt) {
            int ao = (mt * 16 + cn) * 40 + kg * 8;
            bf16x8 ah = *(const bf16x8*)(A_hi + ao);
            bf16x8 al = *(const bf16x8*)(A_lo + ao);
#pragma unroll
            for (int nt = 0; nt < NT; ++nt) {
                acc[mt][nt] = __builtin_amdgcn_mfma_f32_16x16x32_bf16(al, bh[nt], acc[mt][nt], 0, 0, 0);
                acc[mt][nt] = __builtin_amdgcn_mfma_f32_16x16x32_bf16(ah, bl[nt], acc[mt][nt], 0, 0, 0);
                acc[mt][nt] = __builtin_amdgcn_mfma_f32_16x16x32_bf16(ah, bh[nt], acc[mt][nt], 0, 0, 0);
            }
        }
        __syncthreads();
    }

    unsigned* T = (unsigned*)Abuf2;
    const int b = m0 >> 12;
#pragma unroll
    for (int mt = 0; mt < MT; ++mt) {
#pragma unroll
        for (int nt = 0; nt < NT; ++nt) {
            int col = n0 + (w * NT + nt) * 16 + cn;
            float s = sv[col], bb = bvv[col];
            float cc = (MODE == 1) ? extra[b * 512 + col] : 0.0f;
#pragma unroll
            for (int r = 0; r < 4; ++r) {
                float v = lrelu((acc[mt][nt][r] + cc) * s + bb);
                T[(kg * 4 + r) * 132 + (w * NT + nt) * 16 + cn] = packbf(v);
            }
        }
        __syncthreads();
        {
            int row = t >> 4, c0 = (t & 15) * 8;
            uint4 u0 = *(uint4*)(T + row * 132 + c0);
            uint4 u1 = *(uint4*)(T + row * 132 + c0 + 4);
            int grow = m0 + mt * 16 + row;
            *(uint4*)(op + (size_t)grow * NTOT + n0 + c0) = u0;
            *(uint4*)(op + (size_t)grow * NTOT + n0 + c0 + 4) = u1;
        }
        __syncthreads();
    }
}

// ---------------- MODE 1 GEMM (three packed x-arrays), +c7 epilogue, packed output ----------------
template<int MT, int NT, int KD, int NTOT>
__global__ __launch_bounds__(256) void gemm_mfma_c7(
    const unsigned* __restrict__ A0, const unsigned* __restrict__ A1, const unsigned* __restrict__ A2,
    const short* __restrict__ Bh, const short* __restrict__ Bl,
    const float* __restrict__ sv, const float* __restrict__ bvv,
    const float* __restrict__ extra, unsigned* __restrict__ op)
{
    const int t = threadIdx.x;
    const int w = t >> 6, lane = t & 63;
    const int cn = lane & 15, kg = lane >> 4;
    const int m0 = blockIdx.x * (MT * 16);
    const int n0 = blockIdx.y * (NT * 64);

    __shared__ __align__(16) short Abuf2[2 * MT * 16 * 40 > 2 * 16 * 132 * 2 ? 2 * MT * 16 * 40 : 2 * 16 * 132 * 2];
    short* A_hi = Abuf2;
    short* A_lo = Abuf2 + MT * 16 * 40;

    f32x4 acc[MT][NT];
#pragma unroll
    for (int mt = 0; mt < MT; ++mt)
#pragma unroll
        for (int nt = 0; nt < NT; ++nt) acc[mt][nt] = (f32x4){0.f, 0.f, 0.f, 0.f};

    for (int kc = 0; kc < KD / 32; ++kc) {
        {
            const int kq = (t & 7) * 4;
            const int r0 = t >> 3;
#pragma unroll
            for (int rr = 0; rr < (MT * 16) / 32; ++rr) {
                int row = r0 + rr * 32;
                int gk = kc * 32 + kq;
                const unsigned* srcp = (gk < 64) ? A0 : ((gk < 128) ? A1 : A2);
                uint4 v = *(const uint4*)(srcp + (size_t)(m0 + row) * 64 + (gk & 63));
                short4 h, l;
                h.x = (short)(v.x >> 16); l.x = (short)v.x;
                h.y = (short)(v.y >> 16); l.y = (short)v.y;
                h.z = (short)(v.z >> 16); l.z = (short)v.z;
                h.w = (short)(v.w >> 16); l.w = (short)v.w;
                *(short4*)(A_hi + row * 40 + kq) = h;
                *(short4*)(A_lo + row * 40 + kq) = l;
            }
        }
        __syncthreads();
        bf16x8 bh[NT], bl[NT];
#pragma unroll
        for (int nt = 0; nt < NT; ++nt) {
            int col = n0 + (w * NT + nt) * 16 + cn;
            int boff = col * KD + kc * 32 + kg * 8;
            bh[nt] = *(const bf16x8*)(Bh + boff);
            bl[nt] = *(const bf16x8*)(Bl + boff);
        }
#pragma unroll
        for (int mt = 0; mt < MT; ++mt) {
            int ao = (mt * 16 + cn) * 40 + kg * 8;
            bf16x8 ah = *(const bf16x8*)(A_hi + ao);
            bf16x8 al = *(const bf16x8*)(A_lo + ao);
#pragma unroll
            for (int nt = 0; nt < NT; ++nt) {
                acc[mt][nt] = __builtin_amdgcn_mfma_f32_16x16x32_bf16(al, bh[nt], acc[mt][nt], 0, 0, 0);
                acc[mt][nt] = __builtin_amdgcn_mfma_f32_16x16x32_bf16(ah, bl[nt], acc[mt][nt], 0, 0, 0);
                acc[mt][nt] = __builtin_amdgcn_mfma_f32_16x16x32_bf16(ah, bh[nt], acc[mt][nt], 0, 0, 0);
            }
        }
        __syncthreads();
    }

    unsigned* T = (unsigned*)Abuf2;
    const int b = m0 >> 12;
#pragma unroll
    for (int mt = 0; mt < MT; ++mt) {
#pragma unroll
        for (int nt = 0; nt < NT; ++nt) {
            int col = n0 + (w * NT + nt) * 16 + cn;
            float s = sv[col], bb = bvv[col];
            float cc = extra[b * 512 + col];
#pragma unroll
            for (int r = 0; r < 4; ++r) {
                float v = lrelu((acc[mt][nt][r] + cc) * s + bb);
                T[(kg * 4 + r) * 132 + (w * NT + nt) * 16 + cn] = packbf(v);
            }
        }
        __syncthreads();
        {
            int row = t >> 4, c0 = (t & 15) * 8;
            uint4 u0 = *(uint4*)(T + row * 132 + c0);
            uint4 u1 = *(uint4*)(T + row * 132 + c0 + 4);
            int grow = m0 + mt * 16 + row;
            *(uint4*)(op + (size_t)grow * NTOT + n0 + c0) = u0;
            *(uint4*)(op + (size_t)grow * NTOT + n0 + c0 + 4) = u1;
        }
        __syncthreads();
    }
}

__global__ __launch_bounds__(256) void greduce_kernel(const float* __restrict__ gpart, float* __restrict__ g)
{
    int tid = blockIdx.x * 256 + threadIdx.x;   // 4096
    int b = tid >> 10, o = tid & 1023;
    float m = -1e30f;
    for (int q = 0; q < 32; ++q) m = fmaxf(m, gpart[(b * 32 + q) * 1024 + o]);
    g[tid] = m;
}

__global__ __launch_bounds__(256) void c7_kernel(const float* __restrict__ g, const float* __restrict__ W7,
                                                 float* __restrict__ c7)
{
    int tid = blockIdx.x * 256 + threadIdx.x;   // 2048
    int b = tid >> 9, o = tid & 511;
    const float* gb = g + b * 1024;
    const float* wr = W7 + o * 1216;
    float s = 0.0f;
    for (int i = 0; i < 1024; i += 4) {
        float4 wv4 = *reinterpret_cast<const float4*>(&wr[i]);
        float4 gv4 = *reinterpret_cast<const float4*>(&gb[i]);
        s += wv4.x * gv4.x + wv4.y * gv4.y + wv4.z * gv4.z + wv4.w * gv4.w;
    }
    c7[tid] = s;
}

extern "C" void kernel_launch(void* const* d_in, const int* in_sizes, int n_in,
                              void* d_out, int out_size, void* d_ws, size_t ws_size,
                              hipStream_t stream)
{
    const float* x  = (const float*)d_in[0];
    const float* W1 = (const float*)d_in[1];
    const float* s1 = (const float*)d_in[2];
    const float* b1 = (const float*)d_in[3];
    const float* W2 = (const float*)d_in[4];
    const float* s2 = (const float*)d_in[5];
    const float* b2 = (const float*)d_in[6];
    const float* W3 = (const float*)d_in[7];
    const float* s3 = (const float*)d_in[8];
    const float* b3 = (const float*)d_in[9];
    const float* W4 = (const float*)d_in[10];
    const float* s4 = (const float*)d_in[11];
    const float* b4 = (const float*)d_in[12];
    const float* W5 = (const float*)d_in[13];
    const float* s5 = (const float*)d_in[14];
    const float* b5 = (const float*)d_in[15];
    const float* W6 = (const float*)d_in[16];
    const float* s6 = (const float*)d_in[17];
    const float* b6 = (const float*)d_in[18];
    const float* W7 = (const float*)d_in[19];
    const float* s7 = (const float*)d_in[20];
    const float* b7 = (const float*)d_in[21];
    const float* W8 = (const float*)d_in[22];
    const float* s8 = (const float*)d_in[23];
    const float* b8 = (const float*)d_in[24];
    const float* W9 = (const float*)d_in[25];
    const float* b9 = (const float*)d_in[26];

    char* ws = (char*)d_ws;
    int*      idx   = (int*)(ws);                      // 2.62 MB
    float*    x1    = (float*)(ws + 2621440);
    float*    x2    = (float*)(ws + 6815744);
    float*    x3    = (float*)(ws + 11010048);
    unsigned* x1p   = (unsigned*)(ws + 15204352);
    unsigned* x2p   = (unsigned*)(ws + 19398656);
    unsigned* x3p   = (unsigned*)(ws + 23592960);
    float*    gpart = (float*)(ws + 27787264);         // 128*1024
    float*    g     = (float*)(ws + 28311552);
    float*    c7    = (float*)(ws + 28327936);
    short*    w3h   = (short*)(ws + 28336128);
    short*    w3l   = w3h + 4096;
    short*    w4h   = w3h + 8192;
    short*    w4l   = w3h + 12288;
    short*    w5h   = w3h + 16384;
    short*    w5l   = w3h + 20480;
    float*    wdt3  = (float*)(ws + 28385280);
    float*    wdt5  = (float*)(ws + 28401664);
    short*    w6h   = (short*)(ws + 28418048);         // 196608 shorts
    short*    w6l   = (short*)(ws + 28811264);
    short*    w7h   = (short*)(ws + 29204480);         // 98304
    short*    w7l   = (short*)(ws + 29401088);
    short*    w8h   = (short*)(ws + 29597696);         // 131072
    short*    w8l   = (short*)(ws + 29859840);
    short*    w9h   = (short*)(ws + 30121984);         // 16384
    short*    w9l   = (short*)(ws + 30154752);
    short*    w2h   = (short*)(ws + 30187520);         // 4096 shorts
    short*    w2l   = (short*)(ws + 30195712);
    unsigned* h7p   = (unsigned*)(ws + 30408704);      // 33.55 MB -> ends 63963136
    unsigned* h8p   = (unsigned*)(ws);                 // 16.78 MB, aliases dead early buffers
    float*    outp  = (float*)d_out;

    knn_kernel<<<BATCH * N_PTS, 256, 0, stream>>>(x, idx);
    prep_kernel<<<16, 256, 0, stream>>>(W2, W3, W4, W5, w2h, w2l, w3h, w3l, w4h, w4l, w5h, w5l, wdt3, wdt5);
    prep2_kernel<<<1728, 256, 0, stream>>>(W6, W7, W8, W9, w6h, w6l, w7h, w7l, w8h, w8l, w9h, w9l);
    layer1_mfma_kernel<<<BATCH * N_PTS / 2, 256, 0, stream>>>(x, idx, W1, s1, b1, w2h, w2l, s2, b2, x1, x1p);
    edge_mfma_kernel<1><<<BATCH * N_PTS / 2, 256, 0, stream>>>(x1, idx, w3h, w3l, wdt3, s3, b3, w4h, w4l, s4, b4, x2, x2p);
    edge_mfma_kernel<0><<<BATCH * N_PTS / 2, 256, 0, stream>>>(x2, idx, w5h, w5l, wdt5, s5, b5, nullptr, nullptr, nullptr, nullptr, x3, x3p);
    gemm_mfma<0, 8, 2, 192, 1024><<<dim3(128, 8), 256, 0, stream>>>(x1p, x2p, x3p, w6h, w6l, s6, b6, nullptr, gpart);
    greduce_kernel<<<16, 256, 0, stream>>>(gpart, g);
    c7_kernel<<<8, 256, 0, stream>>>(g, W7, c7);
    gemm_mfma_c7<8, 2, 192, 512><<<dim3(128, 4), 256, 0, stream>>>(x1p, x2p, x3p, w7h, w7l, s7, b7, c7, h7p);
    gemm_mfma_t<2, 4, 2, 512, 256><<<dim3(256, 2), 256, 0, stream>>>(h7p, w8h, w8l, s8, b8, nullptr, h8p);
    gemm_mfma<3, 4, 1, 256, 64><<<dim3(256, 1), 256, 0, stream>>>(h8p, nullptr, nullptr, w9h, w9l, nullptr, b9, nullptr, outp);
}

// Round 6
// 474.039 us; speedup vs baseline: 2.2970x; 1.0860x over previous
//
#include <hip/hip_runtime.h>

#define N_PTS 4096
#define KNBR 40
#define BATCH 4

typedef __attribute__((ext_vector_type(8))) short bf16x8;
typedef __attribute__((ext_vector_type(4))) float f32x4;

__device__ __forceinline__ float lrelu(float v) { return v > 0.0f ? v : 0.2f * v; }

__device__ __forceinline__ short bf16_rn(float f) {
    unsigned u = __float_as_uint(f);
    unsigned r = (u + 0x7FFFu + ((u >> 16) & 1u)) >> 16;
    return (short)r;
}
__device__ __forceinline__ float bf16f(short h) {
    return __uint_as_float(((unsigned)(unsigned short)h) << 16);
}
__device__ __forceinline__ unsigned packbf(float v) {
    short h = bf16_rn(v);
    float r = v - bf16f(h);
    short l = bf16_rn(r);
    return (((unsigned)(unsigned short)h) << 16) | (unsigned)(unsigned short)l;
}

// ---------------- KNN: exact top-40 via radix bin select + candidate rank ----------------
__global__ __launch_bounds__(256) void knn_kernel(const float* __restrict__ x, int* __restrict__ idxo)
{
    const int t = threadIdx.x;
    const int pt = blockIdx.x;
    const int b = pt >> 12, n = pt & 4095;
    const float* xb = x + b * 3 * N_PTS;
    const int lane = t & 63, wv = t >> 6;

    __shared__ unsigned hist[4096];
    __shared__ unsigned wtot[4];
    __shared__ int sh[8];          // 0:B1 1:nAbove1 2:needRef 3:emitPos 6:candCnt 7:R1
    unsigned* cov = hist;          // reused after bin select
    int* cidx = (int*)(hist + 2048);

    const float c0 = xb[n], c1 = xb[N_PTS + n], c2 = xb[2 * N_PTS + n];
    const float cc = c0 * c0 + c1 * c1 + c2 * c2;

    unsigned ov[16];
#pragma unroll
    for (int j = 0; j < 16; ++j) {
        int m = t + j * 256;
        float a0 = xb[m], a1 = xb[N_PTS + m], a2 = xb[2 * N_PTS + m];
        float d = 2.0f * (c0 * a0 + c1 * a1 + c2 * a2) - cc - (a0 * a0 + a1 * a1 + a2 * a2);
        unsigned u = __float_as_uint(d);
        ov[j] = (u & 0x80000000u) ? ~u : (u | 0x80000000u);
    }

#pragma unroll
    for (int j = 0; j < 16; ++j) hist[t + j * 256] = 0;
    if (t < 8) sh[t] = 0;
    __syncthreads();
#pragma unroll
    for (int j = 0; j < 16; ++j) atomicAdd(&hist[ov[j] >> 20], 1u);
    __syncthreads();

    // chunk sums + suffix scan (chunk t = bins [16t,16t+16))
    unsigned cs = 0;
#pragma unroll
    for (int q = 0; q < 16; ++q) cs += hist[t * 16 + q];
    unsigned val = cs;
#pragma unroll
    for (int off = 1; off < 64; off <<= 1) {
        unsigned o = __shfl_down(val, off, 64);
        if (lane + off < 64) val += o;
    }
    if (lane == 0) wtot[wv] = val;
    __syncthreads();
    unsigned above_w = 0;
    for (int q = wv + 1; q < 4; ++q) above_w += wtot[q];
    unsigned Sincl = val + above_w;
    unsigned excl = Sincl - cs;
    if (excl < KNBR && Sincl >= KNBR) { sh[0] = t; sh[1] = (int)excl; }
    __syncthreads();
    if (t == 0) {
        int tstar = sh[0];
        unsigned run = (unsigned)sh[1];
        int B1 = -1; unsigned nab = 0;
        for (int q = 15; q >= 0; --q) {
            int bb = tstar * 16 + q;
            unsigned h = hist[bb];
            if (run + h >= KNBR) { B1 = bb; nab = run; break; }
            run += h;
        }
        sh[0] = B1; sh[1] = (int)nab;
        int R1 = KNBR - (int)nab;
        sh[7] = R1;
        sh[2] = ((int)hist[B1] > R1) ? 1 : 0;   // refinement needed?
    }
    __syncthreads();
    const unsigned B1 = (unsigned)sh[0];
    const int needRef = sh[2];
    const int R1 = sh[7];
    const int nab = sh[1];

    // emit strictly-above-bin; collect in-bin candidates (hist memory reused)
#pragma unroll
    for (int j = 0; j < 16; ++j) {
        unsigned bb = ov[j] >> 20;
        if (bb > B1) { int p = atomicAdd(&sh[3], 1); idxo[pt * KNBR + p] = t + j * 256; }
        else if (bb == B1) {
            if (!needRef) { int p = atomicAdd(&sh[3], 1); idxo[pt * KNBR + p] = t + j * 256; }
            else { int q = atomicAdd(&sh[6], 1); if (q < 2048) { cov[q] = ov[j]; cidx[q] = t + j * 256; } }
        }
    }
    if (!needRef) return;
    __syncthreads();
    const int C = sh[6] < 2048 ? sh[6] : 2048;
    // exact rank (value desc, index asc tie-break); broadcast LDS reads
    for (int j = t; j < C; j += 256) {
        unsigned myv = cov[j]; int myi = cidx[j];
        int rank = 0;
        for (int q = 0; q < C; ++q) {
            unsigned v = cov[q];
            rank += (v > myv || (v == myv && cidx[q] < myi)) ? 1 : 0;
        }
        if (rank < R1) idxo[pt * KNBR + nab + rank] = myi;
    }
}

// ---------------- Layer 1 via MFMA: conv1(6->64 VALU) + conv2(64->64 MFMA) + max, 2 pts/block ----------------
__global__ __launch_bounds__(256) void layer1_mfma_kernel(const float* __restrict__ x, const int* __restrict__ idx,
    const float* __restrict__ W1, const float* __restrict__ s1, const float* __restrict__ b1,
    const short* __restrict__ w2h, const short* __restrict__ w2l,
    const float* __restrict__ s2, const float* __restrict__ b2,
    unsigned* __restrict__ x1p)
{
    const int t = threadIdx.x;
    const int pt0 = blockIdx.x * 2;
    const int b = pt0 >> 12;
    const float* xb = x + b * 3 * N_PTS;
    const int lane = t & 63, w = t >> 6;
    const int cn = lane & 15, kg = lane >> 4;

    __shared__ int idxs[80];
    __shared__ float w1t[384];          // [6][64] transposed W1
    __shared__ float ctrv[2][64];
    __shared__ float nbrc[80][4];
    __shared__ float Abuf[5808];
    short* A_hi = (short*)Abuf;
    short* A_lo = A_hi + 80 * 72;
    float* red = Abuf;

    if (t < 80) idxs[t] = idx[pt0 * KNBR + t];
    if (t < 64) {
#pragma unroll
        for (int j = 0; j < 6; ++j) w1t[j * 64 + t] = W1[t * 6 + j];
    }
    __syncthreads();
    if (t < 240) { int k = t / 3, j = t % 3; nbrc[k][j] = xb[j * N_PTS + idxs[k]]; }
    if (t < 128) {
        int p = t >> 6, o = t & 63;
        int n = (pt0 + p) & 4095;
        float cx = xb[n], cy = xb[N_PTS + n], cz = xb[2 * N_PTS + n];
        ctrv[p][o] = (w1t[192 + o] - w1t[o]) * cx + (w1t[256 + o] - w1t[64 + o]) * cy
                   + (w1t[320 + o] - w1t[128 + o]) * cz;
    }
    bf16x8 bh[2], bl[2];
#pragma unroll
    for (int kc = 0; kc < 2; ++kc) {
        int off = (w * 16 + cn) * 64 + kc * 32 + kg * 8;
        bh[kc] = *(const bf16x8*)(w2h + off);
        bl[kc] = *(const bf16x8*)(w2l + off);
    }
    __syncthreads();
    {
        const int o = t & 63;
        const float w0 = w1t[o], w1v = w1t[64 + o], w2v = w1t[128 + o];
        const float sv = s1[o], bv = b1[o];
        const float cv0 = ctrv[0][o], cv1 = ctrv[1][o];
#pragma unroll
        for (int r = 0; r < 20; ++r) {
            int k = (t >> 6) + r * 4;
            float v = w0 * nbrc[k][0] + w1v * nbrc[k][1] + w2v * nbrc[k][2] + (k >= KNBR ? cv1 : cv0);
            v = lrelu(v * sv + bv);
            short h = bf16_rn(v);
            A_hi[k * 72 + o] = h;
            A_lo[k * 72 + o] = bf16_rn(v - bf16f(h));
        }
    }
    __syncthreads();
    f32x4 acc[5];
#pragma unroll
    for (int mt = 0; mt < 5; ++mt) {
        f32x4 a = {0.f, 0.f, 0.f, 0.f};
#pragma unroll
        for (int kc = 0; kc < 2; ++kc) {
            int ao = (mt * 16 + cn) * 72 + kc * 32 + kg * 8;
            bf16x8 ah = *(const bf16x8*)(A_hi + ao);
            bf16x8 al = *(const bf16x8*)(A_lo + ao);
            a = __builtin_amdgcn_mfma_f32_16x16x32_bf16(al, bh[kc], a, 0, 0, 0);
            a = __builtin_amdgcn_mfma_f32_16x16x32_bf16(ah, bl[kc], a, 0, 0, 0);
            a = __builtin_amdgcn_mfma_f32_16x16x32_bf16(ah, bh[kc], a, 0, 0, 0);
        }
        acc[mt] = a;
    }
    const int o1 = w * 16 + cn;
    const float sB = s2[o1], bB = b2[o1];
    __syncthreads();
#pragma unroll
    for (int mt = 0; mt < 5; ++mt)
#pragma unroll
        for (int reg = 0; reg < 4; ++reg) {
            int row = mt * 16 + kg * 4 + reg;
            red[row * 68 + o1] = lrelu(acc[mt][reg] * sB + bB);
        }
    __syncthreads();
    if (t < 128) {
        int p = t >> 6, o = t & 63;
        float m = -1e30f;
#pragma unroll 8
        for (int k = 0; k < KNBR; ++k) m = fmaxf(m, red[(p * KNBR + k) * 68 + o]);
        x1p[(pt0 + p) * 64 + o] = packbf(m);
    }
}

// ---------------- prep: edge-conv + W2 weights -> bf16 hi/lo + ctr-weight transpose ----------------
__global__ __launch_bounds__(256) void prep_kernel(const float* __restrict__ W2, const float* __restrict__ W3,
    const float* __restrict__ W4, const float* __restrict__ W5,
    short* __restrict__ w2h, short* __restrict__ w2l,
    short* __restrict__ w3h, short* __restrict__ w3l,
    short* __restrict__ w4h, short* __restrict__ w4l,
    short* __restrict__ w5h, short* __restrict__ w5l,
    float* __restrict__ wdt3, float* __restrict__ wdt5)
{
    int e = blockIdx.x * 256 + threadIdx.x;   // 4096
    int o = e >> 6, i = e & 63;
    float a = W3[o * 128 + i];
    short h = bf16_rn(a);
    w3h[e] = h; w3l[e] = bf16_rn(a - bf16f(h));
    wdt3[i * 64 + o] = W3[o * 128 + 64 + i] - a;
    float c = W4[o * 64 + i];
    h = bf16_rn(c);
    w4h[e] = h; w4l[e] = bf16_rn(c - bf16f(h));
    float d = W5[o * 128 + i];
    h = bf16_rn(d);
    w5h[e] = h; w5l[e] = bf16_rn(d - bf16f(h));
    wdt5[i * 64 + o] = W5[o * 128 + 64 + i] - d;
    float e2 = W2[o * 64 + i];
    h = bf16_rn(e2);
    w2h[e] = h; w2l[e] = bf16_rn(e2 - bf16f(h));
}

// ---------------- prep2: W6/W7(slice)/W8/W9 -> split bf16 hi/lo ----------------
__global__ __launch_bounds__(256) void prep2_kernel(const float* __restrict__ W6, const float* __restrict__ W7,
    const float* __restrict__ W8, const float* __restrict__ W9,
    short* __restrict__ w6h, short* __restrict__ w6l,
    short* __restrict__ w7h, short* __restrict__ w7l,
    short* __restrict__ w8h, short* __restrict__ w8l,
    short* __restrict__ w9h, short* __restrict__ w9l)
{
    int e = blockIdx.x * 256 + threadIdx.x;
    float v; short* dh; short* dl; int di;
    if (e < 196608) {
        v = W6[e]; dh = w6h; dl = w6l; di = e;
    } else if (e < 294912) {
        int ee = e - 196608;
        int o = ee / 192, k = ee - o * 192;
        v = W7[o * 1216 + 1024 + k]; dh = w7h; dl = w7l; di = ee;
    } else if (e < 425984) {
        int ee = e - 294912;
        v = W8[ee]; dh = w8h; dl = w8l; di = ee;
    } else if (e < 442368) {
        int ee = e - 425984;
        int o = ee >> 8, k = ee & 255;
        v = (o < 63) ? W9[o * 256 + k] : 0.0f;
        dh = w9h; dl = w9l; di = ee;
    } else return;
    short h = bf16_rn(v);
    dh[di] = h; dl[di] = bf16_rn(v - bf16f(h));
}

// ---------------- Edge layers via MFMA (split-bf16), packed input, 2 points/block, M=80 ----------------
template<int HAS2>
__global__ __launch_bounds__(256) void edge_mfma_kernel(const unsigned* __restrict__ srcp, const int* __restrict__ idx,
    const short* __restrict__ wah, const short* __restrict__ wal, const float* __restrict__ wdt,
    const float* __restrict__ sa, const float* __restrict__ ba,
    const short* __restrict__ wbh, const short* __restrict__ wbl,
    const float* __restrict__ sb, const float* __restrict__ bb,
    unsigned* __restrict__ xpout)
{
    const int t = threadIdx.x;
    const int pt0 = blockIdx.x * 2;
    const int b = pt0 >> 12;
    const int lane = t & 63, w = t >> 6;
    const int cn = lane & 15, kg = lane >> 4;

    __shared__ int idxs[80];
    __shared__ float ctr1[2][64];
    __shared__ float part[2][2][64];
    __shared__ float Abuf[5808];
    short* A_hi = (short*)Abuf;
    short* A_lo = A_hi + 80 * 72;
    float* red = Abuf;

    if (t < 80) idxs[t] = idx[pt0 * KNBR + t];
    if (t >= 128) {
        int p = (t >> 6) & 1; int i = t & 63;
        unsigned u = srcp[(pt0 + p) * 64 + i];
        ctr1[p][i] = bf16f((short)(u >> 16)) + bf16f((short)u);
    }
    __syncthreads();

    bf16x8 bh[2], bl[2];
#pragma unroll
    for (int kc = 0; kc < 2; ++kc) {
        int off = (w * 16 + cn) * 64 + kc * 32 + kg * 8;
        bh[kc] = *(const bf16x8*)(wah + off);
        bl[kc] = *(const bf16x8*)(wal + off);
    }

    // gather packed neighbors -> unpack to hi/lo LDS planes (2 shifts/elem)
    {
        const int r0 = t >> 4, c4 = (t & 15) * 4;
#pragma unroll
        for (int r = 0; r < 5; ++r) {
            int row = r * 16 + r0;
            uint4 v = *(const uint4*)(srcp + (size_t)(b * N_PTS + idxs[row]) * 64 + c4);
            short4 h, l;
            h.x = (short)(v.x >> 16); l.x = (short)v.x;
            h.y = (short)(v.y >> 16); l.y = (short)v.y;
            h.z = (short)(v.z >> 16); l.z = (short)v.z;
            h.w = (short)(v.w >> 16); l.w = (short)v.w;
            *(short4*)(A_hi + row * 72 + c4) = h;
            *(short4*)(A_lo + row * 72 + c4) = l;
        }
    }
    // ctrv partials across all 256 threads (32 FMAs each)
    {
        int p = t >> 7, half = (t >> 6) & 1, o = t & 63;
        const float* wp = wdt + half * 32 * 64 + o;
        float s = 0.0f;
#pragma unroll 8
        for (int i = 0; i < 32; ++i) s = fmaf(wp[i * 64], ctr1[p][half * 32 + i], s);
        part[p][half][o] = s;
    }
    __syncthreads();

    f32x4 acc[5];
#pragma unroll
    for (int mt = 0; mt < 5; ++mt) {
        f32x4 a = {0.f, 0.f, 0.f, 0.f};
#pragma unroll
        for (int kc = 0; kc < 2; ++kc) {
            int ao = (mt * 16 + cn) * 72 + kc * 32 + kg * 8;
            bf16x8 ah = *(const bf16x8*)(A_hi + ao);
            bf16x8 al = *(const bf16x8*)(A_lo + ao);
            a = __builtin_amdgcn_mfma_f32_16x16x32_bf16(al, bh[kc], a, 0, 0, 0);
            a = __builtin_amdgcn_mfma_f32_16x16x32_bf16(ah, bl[kc], a, 0, 0, 0);
            a = __builtin_amdgcn_mfma_f32_16x16x32_bf16(ah, bh[kc], a, 0, 0, 0);
        }
        acc[mt] = a;
    }

    const int o1 = w * 16 + cn;
    const float cv0 = part[0][0][o1] + part[0][1][o1];
    const float cv1 = part[1][0][o1] + part[1][1][o1];
    const float sA = sa[o1], bA = ba[o1];
    __syncthreads();

    if (HAS2) {
#pragma unroll
        for (int mt = 0; mt < 5; ++mt) {
#pragma unroll
            for (int reg = 0; reg < 4; ++reg) {
                int row = mt * 16 + kg * 4 + reg;
                float v = lrelu((acc[mt][reg] + (row >= KNBR ? cv1 : cv0)) * sA + bA);
                short h = bf16_rn(v);
                A_hi[row * 72 + o1] = h;
                A_lo[row * 72 + o1] = bf16_rn(v - bf16f(h));
            }
        }
        __syncthreads();
#pragma unroll
        for (int kc = 0; kc < 2; ++kc) {
            int off = (w * 16 + cn) * 64 + kc * 32 + kg * 8;
            bh[kc] = *(const bf16x8*)(wbh + off);
            bl[kc] = *(const bf16x8*)(wbl + off);
        }
#pragma unroll
        for (int mt = 0; mt < 5; ++mt) {
            f32x4 a = {0.f, 0.f, 0.f, 0.f};
#pragma unroll
            for (int kc = 0; kc < 2; ++kc) {
                int ao = (mt * 16 + cn) * 72 + kc * 32 + kg * 8;
                bf16x8 ah = *(const bf16x8*)(A_hi + ao);
                bf16x8 al = *(const bf16x8*)(A_lo + ao);
                a = __builtin_amdgcn_mfma_f32_16x16x32_bf16(al, bh[kc], a, 0, 0, 0);
                a = __builtin_amdgcn_mfma_f32_16x16x32_bf16(ah, bl[kc], a, 0, 0, 0);
                a = __builtin_amdgcn_mfma_f32_16x16x32_bf16(ah, bh[kc], a, 0, 0, 0);
            }
            acc[mt] = a;
        }
        const float sB = sb[o1], bB = bb[o1];
        __syncthreads();
#pragma unroll
        for (int mt = 0; mt < 5; ++mt) {
#pragma unroll
            for (int reg = 0; reg < 4; ++reg) {
                int row = mt * 16 + kg * 4 + reg;
                red[row * 68 + o1] = lrelu(acc[mt][reg] * sB + bB);
            }
        }
    } else {
#pragma unroll
        for (int mt = 0; mt < 5; ++mt) {
#pragma unroll
            for (int reg = 0; reg < 4; ++reg) {
                int row = mt * 16 + kg * 4 + reg;
                red[row * 68 + o1] = lrelu((acc[mt][reg] + (row >= KNBR ? cv1 : cv0)) * sA + bA);
            }
        }
    }
    __syncthreads();
    if (t < 128) {
        int p = t >> 6, o = t & 63;
        float m = -1e30f;
#pragma unroll 8
        for (int k = 0; k < KNBR; ++k) m = fmaxf(m, red[(p * KNBR + k) * 68 + o]);
        xpout[(pt0 + p) * 64 + o] = packbf(m);
    }
}

// ---------------- Split-bf16 MFMA GEMM, fused epilogues ----------------
// MODE 0: conv6 (A=x123p K=192, lrelu, per-block col-max -> gpart)
// MODE 3: conv9 (A=h8p K=256, +b9, transposed fp32 store, col<63)
template<int MODE, int MT, int NT, int KD, int NTOT>
__global__ __launch_bounds__(256) void gemm_mfma(
    const unsigned* __restrict__ A0, const unsigned* __restrict__ A1, const unsigned* __restrict__ A2,
    const short* __restrict__ Bh, const short* __restrict__ Bl,
    const float* __restrict__ sv, const float* __restrict__ bvv,
    const float* __restrict__ extra, void* __restrict__ outp)
{
    const int t = threadIdx.x;
    const int w = t >> 6, lane = t & 63;
    const int cn = lane & 15, kg = lane >> 4;
    const int m0 = blockIdx.x * (MT * 16);
    const int n0 = blockIdx.y * (NT * 64);

    __shared__ __align__(16) short Abuf2[2 * MT * 16 * 40];
    short* A_hi = Abuf2;
    short* A_lo = Abuf2 + MT * 16 * 40;

    f32x4 acc[MT][NT];
#pragma unroll
    for (int mt = 0; mt < MT; ++mt)
#pragma unroll
        for (int nt = 0; nt < NT; ++nt) acc[mt][nt] = (f32x4){0.f, 0.f, 0.f, 0.f};

    for (int kc = 0; kc < KD / 32; ++kc) {
        {
            const int kq = (t & 7) * 4;
            const int r0 = t >> 3;
#pragma unroll
            for (int rr = 0; rr < (MT * 16) / 32; ++rr) {
                int row = r0 + rr * 32;
                int gk = kc * 32 + kq;
                uint4 v;
                if (MODE == 0) {
                    const unsigned* srcp = (gk < 64) ? A0 : ((gk < 128) ? A1 : A2);
                    v = *(const uint4*)(srcp + (size_t)(m0 + row) * 64 + (gk & 63));
                } else {
                    v = *(const uint4*)(A0 + (size_t)(m0 + row) * KD + gk);
                }
                short4 h, l;
                h.x = (short)(v.x >> 16); l.x = (short)v.x;
                h.y = (short)(v.y >> 16); l.y = (short)v.y;
                h.z = (short)(v.z >> 16); l.z = (short)v.z;
                h.w = (short)(v.w >> 16); l.w = (short)v.w;
                *(short4*)(A_hi + row * 40 + kq) = h;
                *(short4*)(A_lo + row * 40 + kq) = l;
            }
        }
        __syncthreads();
        bf16x8 bh[NT], bl[NT];
#pragma unroll
        for (int nt = 0; nt < NT; ++nt) {
            int col = n0 + (w * NT + nt) * 16 + cn;
            int boff = col * KD + kc * 32 + kg * 8;
            bh[nt] = *(const bf16x8*)(Bh + boff);
            bl[nt] = *(const bf16x8*)(Bl + boff);
        }
#pragma unroll
        for (int mt = 0; mt < MT; ++mt) {
            int ao = (mt * 16 + cn) * 40 + kg * 8;
            bf16x8 ah = *(const bf16x8*)(A_hi + ao);
            bf16x8 al = *(const bf16x8*)(A_lo + ao);
#pragma unroll
            for (int nt = 0; nt < NT; ++nt) {
                acc[mt][nt] = __builtin_amdgcn_mfma_f32_16x16x32_bf16(al, bh[nt], acc[mt][nt], 0, 0, 0);
                acc[mt][nt] = __builtin_amdgcn_mfma_f32_16x16x32_bf16(ah, bl[nt], acc[mt][nt], 0, 0, 0);
                acc[mt][nt] = __builtin_amdgcn_mfma_f32_16x16x32_bf16(ah, bh[nt], acc[mt][nt], 0, 0, 0);
            }
        }
        __syncthreads();
    }

    if (MODE == 0) {
        float* gp = (float*)outp;
#pragma unroll
        for (int nt = 0; nt < NT; ++nt) {
            int col = n0 + (w * NT + nt) * 16 + cn;
            float s = sv[col], bb = bvv[col];
            float mx = -1e30f;
#pragma unroll
            for (int mt = 0; mt < MT; ++mt)
#pragma unroll
                for (int r = 0; r < 4; ++r) mx = fmaxf(mx, lrelu(acc[mt][nt][r] * s + bb));
            mx = fmaxf(mx, __shfl_xor(mx, 16, 64));
            mx = fmaxf(mx, __shfl_xor(mx, 32, 64));
            if (kg == 0) gp[blockIdx.x * NTOT + col] = mx;
        }
    } else {
        float* of = (float*)outp;
        const int b = m0 >> 12;
        const int nrow0 = m0 & 4095;
        int col = w * 16 + cn;
        if (col < 63) {
            float bb = bvv[col];
#pragma unroll
            for (int mt = 0; mt < MT; ++mt) {
                float4 o4;
                o4.x = acc[mt][0][0] + bb; o4.y = acc[mt][0][1] + bb;
                o4.z = acc[mt][0][2] + bb; o4.w = acc[mt][0][3] + bb;
                *(float4*)(of + (size_t)(b * 63 + col) * N_PTS + nrow0 + mt * 16 + kg * 4) = o4;
            }
        }
    }
}

// ---------------- MODE 2-style GEMM (contiguous packed A), packed output via LDS transpose ----------------
template<int MODE, int MT, int NT, int KD, int NTOT>
__global__ __launch_bounds__(256) void gemm_mfma_t(
    const unsigned* __restrict__ A0,
    const short* __restrict__ Bh, const short* __restrict__ Bl,
    const float* __restrict__ sv, const float* __restrict__ bvv,
    const float* __restrict__ extra, unsigned* __restrict__ op)
{
    const int t = threadIdx.x;
    const int w = t >> 6, lane = t & 63;
    const int cn = lane & 15, kg = lane >> 4;
    const int m0 = blockIdx.x * (MT * 16);
    const int n0 = blockIdx.y * (NT * 64);

    __shared__ __align__(16) short Abuf2[2 * MT * 16 * 40 > 2 * 16 * 132 * 2 ? 2 * MT * 16 * 40 : 2 * 16 * 132 * 2];
    short* A_hi = Abuf2;
    short* A_lo = Abuf2 + MT * 16 * 40;

    f32x4 acc[MT][NT];
#pragma unroll
    for (int mt = 0; mt < MT; ++mt)
#pragma unroll
        for (int nt = 0; nt < NT; ++nt) acc[mt][nt] = (f32x4){0.f, 0.f, 0.f, 0.f};

    for (int kc = 0; kc < KD / 32; ++kc) {
        {
            const int kq = (t & 7) * 4;
            const int r0 = t >> 3;
#pragma unroll
            for (int rr = 0; rr < (MT * 16) / 32; ++rr) {
                int row = r0 + rr * 32;
                int gk = kc * 32 + kq;
                uint4 v = *(const uint4*)(A0 + (size_t)(m0 + row) * KD + gk);
                short4 h, l;
                h.x = (short)(v.x >> 16); l.x = (short)v.x;
                h.y = (short)(v.y >> 16); l.y = (short)v.y;
                h.z = (short)(v.z >> 16); l.z = (short)v.z;
                h.w = (short)(v.w >> 16); l.w = (short)v.w;
                *(short4*)(A_hi + row * 40 + kq) = h;
                *(short4*)(A_lo + row * 40 + kq) = l;
            }
        }
        __syncthreads();
        bf16x8 bh[NT], bl[NT];
#pragma unroll
        for (int nt = 0; nt < NT; ++nt) {
            int col = n0 + (w * NT + nt) * 16 + cn;
            int boff = col * KD + kc * 32 + kg * 8;
            bh[nt] = *(const bf16x8*)(Bh + boff);
            bl[nt] = *(const bf16x8*)(Bl + boff);
        }
#pragma unroll
        for (int mt = 0; mt < MT; ++mt) {
            int ao = (mt * 16 + cn) * 40 + kg * 8;
            bf16x8 ah = *(const bf16x8*)(A_hi + ao);
            bf16x8 al = *(const bf16x8*)(A_lo + ao);
#pragma unroll
            for (int nt = 0; nt < NT; ++nt) {
                acc[mt][nt] = __builtin_amdgcn_mfma_f32_16x16x32_bf16(al, bh[nt], acc[mt][nt], 0, 0, 0);
                acc[mt][nt] = __builtin_amdgcn_mfma_f32_16x16x32_bf16(ah, bl[nt], acc[mt][nt], 0, 0, 0);
                acc[mt][nt] = __builtin_amdgcn_mfma_f32_16x16x32_bf16(ah, bh[nt], acc[mt][nt], 0, 0, 0);
            }
        }
        __syncthreads();
    }

    unsigned* T = (unsigned*)Abuf2;
    const int b = m0 >> 12;
#pragma unroll
    for (int mt = 0; mt < MT; ++mt) {
#pragma unroll
        for (int nt = 0; nt < NT; ++nt) {
            int col = n0 + (w * NT + nt) * 16 + cn;
            float s = sv[col], bb = bvv[col];
            float cc = (MODE == 1) ? extra[b * 512 + col] : 0.0f;
#pragma unroll
            for (int r = 0; r < 4; ++r) {
                float v = lrelu((acc[mt][nt][r] + cc) * s + bb);
                T[(kg * 4 + r) * 132 + (w * NT + nt) * 16 + cn] = packbf(v);
            }
        }
        __syncthreads();
        {
            int row = t >> 4, c0 = (t & 15) * 8;
            uint4 u0 = *(uint4*)(T + row * 132 + c0);
            uint4 u1 = *(uint4*)(T + row * 132 + c0 + 4);
            int grow = m0 + mt * 16 + row;
            *(uint4*)(op + (size_t)grow * NTOT + n0 + c0) = u0;
            *(uint4*)(op + (size_t)grow * NTOT + n0 + c0 + 4) = u1;
        }
        __syncthreads();
    }
}

// ---------------- MODE 1 GEMM (three packed x-arrays), +c7 epilogue, packed output ----------------
template<int MT, int NT, int KD, int NTOT>
__global__ __launch_bounds__(256) void gemm_mfma_c7(
    const unsigned* __restrict__ A0, const unsigned* __restrict__ A1, const unsigned* __restrict__ A2,
    const short* __restrict__ Bh, const short* __restrict__ Bl,
    const float* __restrict__ sv, const float* __restrict__ bvv,
    const float* __restrict__ extra, unsigned* __restrict__ op)
{
    const int t = threadIdx.x;
    const int w = t >> 6, lane = t & 63;
    const int cn = lane & 15, kg = lane >> 4;
    const int m0 = blockIdx.x * (MT * 16);
    const int n0 = blockIdx.y * (NT * 64);

    __shared__ __align__(16) short Abuf2[2 * MT * 16 * 40 > 2 * 16 * 132 * 2 ? 2 * MT * 16 * 40 : 2 * 16 * 132 * 2];
    short* A_hi = Abuf2;
    short* A_lo = Abuf2 + MT * 16 * 40;

    f32x4 acc[MT][NT];
#pragma unroll
    for (int mt = 0; mt < MT; ++mt)
#pragma unroll
        for (int nt = 0; nt < NT; ++nt) acc[mt][nt] = (f32x4){0.f, 0.f, 0.f, 0.f};

    for (int kc = 0; kc < KD / 32; ++kc) {
        {
            const int kq = (t & 7) * 4;
            const int r0 = t >> 3;
#pragma unroll
            for (int rr = 0; rr < (MT * 16) / 32; ++rr) {
                int row = r0 + rr * 32;
                int gk = kc * 32 + kq;
                const unsigned* srcp = (gk < 64) ? A0 : ((gk < 128) ? A1 : A2);
                uint4 v = *(const uint4*)(srcp + (size_t)(m0 + row) * 64 + (gk & 63));
                short4 h, l;
                h.x = (short)(v.x >> 16); l.x = (short)v.x;
                h.y = (short)(v.y >> 16); l.y = (short)v.y;
                h.z = (short)(v.z >> 16); l.z = (short)v.z;
                h.w = (short)(v.w >> 16); l.w = (short)v.w;
                *(short4*)(A_hi + row * 40 + kq) = h;
                *(short4*)(A_lo + row * 40 + kq) = l;
            }
        }
        __syncthreads();
        bf16x8 bh[NT], bl[NT];
#pragma unroll
        for (int nt = 0; nt < NT; ++nt) {
            int col = n0 + (w * NT + nt) * 16 + cn;
            int boff = col * KD + kc * 32 + kg * 8;
            bh[nt] = *(const bf16x8*)(Bh + boff);
            bl[nt] = *(const bf16x8*)(Bl + boff);
        }
#pragma unroll
        for (int mt = 0; mt < MT; ++mt) {
            int ao = (mt * 16 + cn) * 40 + kg * 8;
            bf16x8 ah = *(const bf16x8*)(A_hi + ao);
            bf16x8 al = *(const bf16x8*)(A_lo + ao);
#pragma unroll
            for (int nt = 0; nt < NT; ++nt) {
                acc[mt][nt] = __builtin_amdgcn_mfma_f32_16x16x32_bf16(al, bh[nt], acc[mt][nt], 0, 0, 0);
                acc[mt][nt] = __builtin_amdgcn_mfma_f32_16x16x32_bf16(ah, bl[nt], acc[mt][nt], 0, 0, 0);
                acc[mt][nt] = __builtin_amdgcn_mfma_f32_16x16x32_bf16(ah, bh[nt], acc[mt][nt], 0, 0, 0);
            }
        }
        __syncthreads();
    }

    unsigned* T = (unsigned*)Abuf2;
    const int b = m0 >> 12;
#pragma unroll
    for (int mt = 0; mt < MT; ++mt) {
#pragma unroll
        for (int nt = 0; nt < NT; ++nt) {
            int col = n0 + (w * NT + nt) * 16 + cn;
            float s = sv[col], bb = bvv[col];
            float cc = extra[b * 512 + col];
#pragma unroll
            for (int r = 0; r < 4; ++r) {
                float v = lrelu((acc[mt][nt][r] + cc) * s + bb);
                T[(kg * 4 + r) * 132 + (w * NT + nt) * 16 + cn] = packbf(v);
            }
        }
        __syncthreads();
        {
            int row = t >> 4, c0 = (t & 15) * 8;
            uint4 u0 = *(uint4*)(T + row * 132 + c0);
            uint4 u1 = *(uint4*)(T + row * 132 + c0 + 4);
            int grow = m0 + mt * 16 + row;
            *(uint4*)(op + (size_t)grow * NTOT + n0 + c0) = u0;
            *(uint4*)(op + (size_t)grow * NTOT + n0 + c0 + 4) = u1;
        }
        __syncthreads();
    }
}

__global__ __launch_bounds__(256) void greduce_kernel(const float* __restrict__ gpart, float* __restrict__ g)
{
    int tid = blockIdx.x * 256 + threadIdx.x;   // 4096
    int b = tid >> 10, o = tid & 1023;
    float m = -1e30f;
    for (int q = 0; q < 32; ++q) m = fmaxf(m, gpart[(b * 32 + q) * 1024 + o]);
    g[tid] = m;
}

__global__ __launch_bounds__(256) void c7_kernel(const float* __restrict__ g, const float* __restrict__ W7,
                                                 float* __restrict__ c7)
{
    int tid = blockIdx.x * 256 + threadIdx.x;   // 2048
    int b = tid >> 9, o = tid & 511;
    const float* gb = g + b * 1024;
    const float* wr = W7 + o * 1216;
    float s = 0.0f;
    for (int i = 0; i < 1024; i += 4) {
        float4 wv4 = *reinterpret_cast<const float4*>(&wr[i]);
        float4 gv4 = *reinterpret_cast<const float4*>(&gb[i]);
        s += wv4.x * gv4.x + wv4.y * gv4.y + wv4.z * gv4.z + wv4.w * gv4.w;
    }
    c7[tid] = s;
}

extern "C" void kernel_launch(void* const* d_in, const int* in_sizes, int n_in,
                              void* d_out, int out_size, void* d_ws, size_t ws_size,
                              hipStream_t stream)
{
    const float* x  = (const float*)d_in[0];
    const float* W1 = (const float*)d_in[1];
    const float* s1 = (const float*)d_in[2];
    const float* b1 = (const float*)d_in[3];
    const float* W2 = (const float*)d_in[4];
    const float* s2 = (const float*)d_in[5];
    const float* b2 = (const float*)d_in[6];
    const float* W3 = (const float*)d_in[7];
    const float* s3 = (const float*)d_in[8];
    const float* b3 = (const float*)d_in[9];
    const float* W4 = (const float*)d_in[10];
    const float* s4 = (const float*)d_in[11];
    const float* b4 = (const float*)d_in[12];
    const float* W5 = (const float*)d_in[13];
    const float* s5 = (const float*)d_in[14];
    const float* b5 = (const float*)d_in[15];
    const float* W6 = (const float*)d_in[16];
    const float* s6 = (const float*)d_in[17];
    const float* b6 = (const float*)d_in[18];
    const float* W7 = (const float*)d_in[19];
    const float* s7 = (const float*)d_in[20];
    const float* b7 = (const float*)d_in[21];
    const float* W8 = (const float*)d_in[22];
    const float* s8 = (const float*)d_in[23];
    const float* b8 = (const float*)d_in[24];
    const float* W9 = (const float*)d_in[25];
    const float* b9 = (const float*)d_in[26];

    char* ws = (char*)d_ws;
    int*      idx   = (int*)(ws);                      // 2.62 MB
    unsigned* x1p   = (unsigned*)(ws + 15204352);
    unsigned* x2p   = (unsigned*)(ws + 19398656);
    unsigned* x3p   = (unsigned*)(ws + 23592960);
    float*    gpart = (float*)(ws + 27787264);
    float*    g     = (float*)(ws + 28311552);
    float*    c7    = (float*)(ws + 28327936);
    short*    w3h   = (short*)(ws + 28336128);
    short*    w3l   = w3h + 4096;
    short*    w4h   = w3h + 8192;
    short*    w4l   = w3h + 12288;
    short*    w5h   = w3h + 16384;
    short*    w5l   = w3h + 20480;
    float*    wdt3  = (float*)(ws + 28385280);
    float*    wdt5  = (float*)(ws + 28401664);
    short*    w6h   = (short*)(ws + 28418048);
    short*    w6l   = (short*)(ws + 28811264);
    short*    w7h   = (short*)(ws + 29204480);
    short*    w7l   = (short*)(ws + 29401088);
    short*    w8h   = (short*)(ws + 29597696);
    short*    w8l   = (short*)(ws + 29859840);
    short*    w9h   = (short*)(ws + 30121984);
    short*    w9l   = (short*)(ws + 30154752);
    short*    w2h   = (short*)(ws + 30187520);
    short*    w2l   = (short*)(ws + 30195712);
    unsigned* h7p   = (unsigned*)(ws + 30408704);      // 33.55 MB -> ends 63963136
    unsigned* h8p   = (unsigned*)(ws);                 // aliases dead early buffers
    float*    outp  = (float*)d_out;

    knn_kernel<<<BATCH * N_PTS, 256, 0, stream>>>(x, idx);
    prep_kernel<<<16, 256, 0, stream>>>(W2, W3, W4, W5, w2h, w2l, w3h, w3l, w4h, w4l, w5h, w5l, wdt3, wdt5);
    prep2_kernel<<<1728, 256, 0, stream>>>(W6, W7, W8, W9, w6h, w6l, w7h, w7l, w8h, w8l, w9h, w9l);
    layer1_mfma_kernel<<<BATCH * N_PTS / 2, 256, 0, stream>>>(x, idx, W1, s1, b1, w2h, w2l, s2, b2, x1p);
    edge_mfma_kernel<1><<<BATCH * N_PTS / 2, 256, 0, stream>>>(x1p, idx, w3h, w3l, wdt3, s3, b3, w4h, w4l, s4, b4, x2p);
    edge_mfma_kernel<0><<<BATCH * N_PTS / 2, 256, 0, stream>>>(x2p, idx, w5h, w5l, wdt5, s5, b5, nullptr, nullptr, nullptr, nullptr, x3p);
    gemm_mfma<0, 8, 2, 192, 1024><<<dim3(128, 8), 256, 0, stream>>>(x1p, x2p, x3p, w6h, w6l, s6, b6, nullptr, gpart);
    greduce_kernel<<<16, 256, 0, stream>>>(gpart, g);
    c7_kernel<<<8, 256, 0, stream>>>(g, W7, c7);
    gemm_mfma_c7<8, 2, 192, 512><<<dim3(128, 4), 256, 0, stream>>>(x1p, x2p, x3p, w7h, w7l, s7, b7, c7, h7p);
    gemm_mfma_t<2, 4, 2, 512, 256><<<dim3(256, 2), 256, 0, stream>>>(h7p, w8h, w8l, s8, b8, nullptr, h8p);
    gemm_mfma<3, 4, 1, 256, 64><<<dim3(256, 1), 256, 0, stream>>>(h8p, nullptr, nullptr, w9h, w9l, nullptr, b9, nullptr, outp);
}